// Round 3
// baseline (1012.350 us; speedup 1.0000x reference)
//
#include <hip/hip_runtime.h>

#define NB 2
#define NC 64
#define NHW 4096
#define NPIX (NB*NHW)          // 8192
#define SZ   (NB*NC*NHW)       // 524288 floats per 64-ch fp32 tensor

__device__ __forceinline__ float clamp01(float v){ return fminf(fmaxf(v, 0.f), 1.f); }

// ---------------------------------------------------------------- reductions
__global__ __launch_bounds__(256) void k_max_hw(const float* __restrict__ in, float* __restrict__ mx){
  int bc = blockIdx.x; int t = threadIdx.x;
  const float* p = in + (size_t)bc*NHW;
  float m = -1e30f;
  for (int n = t; n < NHW; n += 256) m = fmaxf(m, p[n]);
  #pragma unroll
  for (int off = 32; off; off >>= 1) m = fmaxf(m, __shfl_xor(m, off));
  __shared__ float sm[4];
  if ((t & 63) == 0) sm[t >> 6] = m;
  __syncthreads();
  if (t == 0) mx[bc] = fmaxf(fmaxf(sm[0], sm[1]), fmaxf(sm[2], sm[3]));
}

__global__ void k_spe_score(const float* __restrict__ mx, const float* __restrict__ w,
                            const float* __restrict__ bias, float* __restrict__ out){
  int t = threadIdx.x; if (t >= 128) return;
  int b = t >> 6, o = t & 63;
  float acc = bias[o];
  const float* m = mx + b*64;
  for (int i = 0; i < 64; ++i) acc += w[o*64 + i] * m[i];
  out[t] = clamp01(acc);   // relu6 then clip(-1,1) == clamp to [0,1]
}

__global__ __launch_bounds__(256) void k_chmean(const float* __restrict__ in, float* __restrict__ out){
  int p = blockIdx.x*256 + threadIdx.x;         // 0..8191
  int b = p >> 12, n = p & 4095;
  const float* base = in + (size_t)b*NC*NHW + n;
  float s = 0.f;
  #pragma unroll
  for (int c = 0; c < 64; ++c) s += base[c*NHW];
  out[p] = s * (1.0f/64.0f);
}

// ---------------------------------------------------------------- depthwise 3x3 + score adds
__global__ __launch_bounds__(256) void k_dw3(const float* __restrict__ in, const float* __restrict__ w,
    const float* __restrict__ bias, const float* __restrict__ add_bc, const float* __restrict__ chmean,
    const float* __restrict__ spw, const float* __restrict__ spb, float* __restrict__ out){
  int g = blockIdx.x*256 + threadIdx.x;         // B*64*4096
  int pix = g & 4095; int c = (g >> 12) & 63; int b = g >> 18;
  int y = pix >> 6, x = pix & 63;
  const float* base = in + (size_t)(b*64 + c)*NHW;
  float wf[9];
  #pragma unroll
  for (int i = 0; i < 9; ++i) wf[i] = w[c*9 + i];
  float acc = 0.f;
  #pragma unroll
  for (int ky = -1; ky <= 1; ++ky){
    int yy = y + ky; if ((unsigned)yy >= 64u) continue;
    #pragma unroll
    for (int kx = -1; kx <= 1; ++kx){
      int xx = x + kx; if ((unsigned)xx >= 64u) continue;
      acc += base[yy*64 + xx] * wf[(ky+1)*3 + (kx+1)];
    }
  }
  acc += bias[c];
  if (add_bc) acc += add_bc[b*64 + c];
  if (chmean){
    float z = spw[c] * chmean[b*4096 + pix] + spb[c];
    acc += clamp01(z);
  }
  out[g] = acc;
}

// ---------------------------------------------------------------- pointwise conv (64 -> OC), LDS block GEMM
// grid: (NPIX/64, OC/64); block 256. Per block: 64 out-ch x 64 pixels.
__global__ __launch_bounds__(256) void k_pw(const float* __restrict__ in, const float* __restrict__ w,
    const float* __restrict__ bias, const float* __restrict__ r1, const float* __restrict__ r2,
    float* __restrict__ outf, int OC){
  __shared__ __align__(16) float Xs[64][64];
  __shared__ __align__(16) float Wt[64][64];    // [i][o]
  int t = threadIdx.x;
  int ptile = blockIdx.x; int oc0 = blockIdx.y*64;
  int b = ptile >> 6; int n0 = (ptile & 63)*64;
  const float* inb = in + (size_t)b*64*NHW;
  #pragma unroll
  for (int k = 0; k < 16; ++k){
    int idx = k*256 + t; int i = idx >> 6, n = idx & 63;
    Xs[i][n] = inb[i*NHW + n0 + n];
  }
  #pragma unroll
  for (int k = 0; k < 16; ++k){
    int idx = k*256 + t; int o = idx & 63, i = idx >> 6;
    Wt[i][o] = w[(oc0 + o)*64 + i];
  }
  __syncthreads();
  int tn = t & 15, to = t >> 4;
  float a00=0,a01=0,a02=0,a03=0, a10=0,a11=0,a12=0,a13=0;
  float a20=0,a21=0,a22=0,a23=0, a30=0,a31=0,a32=0,a33=0;
  #pragma unroll
  for (int i = 0; i < 64; ++i){
    const float4 xv = *(const float4*)&Xs[i][tn*4];
    const float4 wv = *(const float4*)&Wt[i][to*4];
    a00 += wv.x*xv.x; a01 += wv.x*xv.y; a02 += wv.x*xv.z; a03 += wv.x*xv.w;
    a10 += wv.y*xv.x; a11 += wv.y*xv.y; a12 += wv.y*xv.z; a13 += wv.y*xv.w;
    a20 += wv.z*xv.x; a21 += wv.z*xv.y; a22 += wv.z*xv.z; a23 += wv.z*xv.w;
    a30 += wv.w*xv.x; a31 += wv.w*xv.y; a32 += wv.w*xv.z; a33 += wv.w*xv.w;
  }
  float accs[4][4] = {{a00,a01,a02,a03},{a10,a11,a12,a13},{a20,a21,a22,a23},{a30,a31,a32,a33}};
  #pragma unroll
  for (int oo = 0; oo < 4; ++oo){
    int o = oc0 + to*4 + oo;
    float bv = bias ? bias[o] : 0.f;
    size_t obase = ((size_t)b*OC + o)*NHW + n0 + tn*4;
    float v0 = accs[oo][0]+bv, v1 = accs[oo][1]+bv, v2 = accs[oo][2]+bv, v3 = accs[oo][3]+bv;
    if (r1){ v0 += r1[obase+0]; v1 += r1[obase+1]; v2 += r1[obase+2]; v3 += r1[obase+3]; }
    if (r2){ v0 += r2[obase+0]; v1 += r2[obase+1]; v2 += r2[obase+2]; v3 += r2[obase+3]; }
    float4 vv; vv.x=v0; vv.y=v1; vv.z=v2; vv.w=v3;
    *(float4*)(outf + obase) = vv;
  }
}

// ---------------------------------------------------------------- flash cross-attention, hd=16, n=4096
// grid: B*HEADS*(4096/32)=1024 blocks, 256 threads = 32 queries x 8 key-splits
__global__ __launch_bounds__(256) void k_flash(const float* __restrict__ Q, const float* __restrict__ K,
                                               const float* __restrict__ V, float* __restrict__ O){
  __shared__ __align__(16) float Ks[16][256];
  __shared__ __align__(16) float Vs[16][256];
  int blk = blockIdx.x;
  int qt = blk & 127; int bh = blk >> 7; int b = bh >> 2, h = bh & 3;
  int t = threadIdx.x;
  int s = t & 7, ql = t >> 3;
  int q = qt*32 + ql;
  size_t cbase = ((size_t)b*64 + h*16)*NHW;
  float qv[16];
  #pragma unroll
  for (int d = 0; d < 16; ++d) qv[d] = Q[cbase + d*NHW + q] * 0.25f;  // fold 1/sqrt(16)
  float m = -1e30f, l = 0.f, acc[16];
  #pragma unroll
  for (int d = 0; d < 16; ++d) acc[d] = 0.f;
  for (int kt = 0; kt < 16; ++kt){
    __syncthreads();
    #pragma unroll
    for (int d = 0; d < 16; ++d){
      Ks[d][t] = K[cbase + d*NHW + kt*256 + t];
      Vs[d][t] = V[cbase + d*NHW + kt*256 + t];
    }
    __syncthreads();
    #pragma unroll
    for (int j = 0; j < 8; ++j){
      int k4 = (s + 8*j)*4;
      float s0=0,s1=0,s2=0,s3=0;
      #pragma unroll
      for (int d = 0; d < 16; ++d){
        const float4 kv = *(const float4*)&Ks[d][k4];
        s0 += qv[d]*kv.x; s1 += qv[d]*kv.y; s2 += qv[d]*kv.z; s3 += qv[d]*kv.w;
      }
      float cm = fmaxf(fmaxf(s0,s1), fmaxf(s2,s3));
      float mn = fmaxf(m, cm);
      float f  = __expf(m - mn);
      float p0 = __expf(s0-mn), p1 = __expf(s1-mn), p2 = __expf(s2-mn), p3 = __expf(s3-mn);
      l = l*f + (p0+p1+p2+p3);
      m = mn;
      #pragma unroll
      for (int d = 0; d < 16; ++d){
        const float4 vv = *(const float4*)&Vs[d][k4];
        acc[d] = acc[d]*f + p0*vv.x + p1*vv.y + p2*vv.z + p3*vv.w;
      }
    }
  }
  // merge 8 splits (consecutive lanes)
  #pragma unroll
  for (int off = 4; off >= 1; off >>= 1){
    float mo = __shfl_xor(m, off);
    float lo = __shfl_xor(l, off);
    float mn = fmaxf(m, mo);
    float fa = __expf(m - mn), fb = __expf(mo - mn);
    l = l*fa + lo*fb;
    #pragma unroll
    for (int d = 0; d < 16; ++d){
      float ao = __shfl_xor(acc[d], off);
      acc[d] = acc[d]*fa + ao*fb;
    }
    m = mn;
  }
  if (s == 0){
    float inv = 1.0f / l;
    #pragma unroll
    for (int d = 0; d < 16; ++d) O[cbase + d*NHW + q] = acc[d]*inv;
  }
}

// ---------------------------------------------------------------- bias-free LayerNorm over channels
__global__ __launch_bounds__(256) void k_ln(const float* __restrict__ in, const float* __restrict__ wln,
                                            float* __restrict__ out){
  int p = blockIdx.x*256 + threadIdx.x;
  int b = p >> 12, n = p & 4095;
  const float* base = in + (size_t)b*64*NHW + n;
  float x[64]; float mu = 0.f;
  #pragma unroll
  for (int c = 0; c < 64; ++c){ x[c] = base[c*NHW]; mu += x[c]; }
  mu *= (1.f/64.f);
  float var = 0.f;
  #pragma unroll
  for (int c = 0; c < 64; ++c){ float d = x[c]-mu; var += d*d; }
  var *= (1.f/64.f);
  float sc = rsqrtf(var + 1e-5f);
  float* ob = out + (size_t)b*64*NHW + n;
  #pragma unroll
  for (int c = 0; c < 64; ++c) ob[c*NHW] = x[c]*sc*wln[c];   // bias-free: x/sigma, no mean subtract
}

// ---------------------------------------------------------------- FFN dw3x3 + chunk + gelu gate (128->64)
__global__ __launch_bounds__(256) void k_dwgate(const float* __restrict__ in, const float* __restrict__ w,
                                                float* __restrict__ out){
  int g = blockIdx.x*256 + threadIdx.x;         // B*64*4096
  int pix = g & 4095; int c = (g >> 12) & 63; int b = g >> 18;
  int y = pix >> 6, x = pix & 63;
  const float* p1 = in + ((size_t)b*128 + c)*NHW;
  const float* p2 = in + ((size_t)b*128 + 64 + c)*NHW;
  float w1[9], w2[9];
  #pragma unroll
  for (int i = 0; i < 9; ++i){ w1[i] = w[c*9+i]; w2[i] = w[(64+c)*9+i]; }
  float a = 0.f, bb = 0.f;
  #pragma unroll
  for (int ky = -1; ky <= 1; ++ky){
    int yy = y + ky; if ((unsigned)yy >= 64u) continue;
    #pragma unroll
    for (int kx = -1; kx <= 1; ++kx){
      int xx = x + kx; if ((unsigned)xx >= 64u) continue;
      int off = yy*64 + xx; int wi = (ky+1)*3 + (kx+1);
      a  += p1[off]*w1[wi];
      bb += p2[off]*w2[wi];
    }
  }
  float gl = 0.5f*a*(1.0f + erff(a*0.70710678118654752f));   // exact gelu
  out[g] = gl*bb;
}

// ---------------------------------------------------------------- dw3x3 on 192 channels (restormer qkv)
__global__ __launch_bounds__(256) void k_dw192(const float* __restrict__ in, const float* __restrict__ w,
                                               float* __restrict__ out){
  int g = blockIdx.x*256 + threadIdx.x;         // B*192*4096
  int pix = g & 4095; int bc = g >> 12; int c = bc % 192;
  int y = pix >> 6, x = pix & 63;
  const float* p = in + (size_t)bc*NHW;
  float wf[9];
  #pragma unroll
  for (int i = 0; i < 9; ++i) wf[i] = w[c*9+i];
  float acc = 0.f;
  #pragma unroll
  for (int ky = -1; ky <= 1; ++ky){
    int yy = y + ky; if ((unsigned)yy >= 64u) continue;
    #pragma unroll
    for (int kx = -1; kx <= 1; ++kx){
      int xx = x + kx; if ((unsigned)xx >= 64u) continue;
      acc += p[yy*64 + xx]*wf[(ky+1)*3 + (kx+1)];
    }
  }
  out[g] = acc;
}

// ---------------------------------------------------------------- elementwise add (float4)
__global__ __launch_bounds__(256) void k_add4(const float4* __restrict__ a, const float4* __restrict__ b,
                                              float4* __restrict__ o){
  int i = blockIdx.x*256 + threadIdx.x;
  float4 x = a[i], y = b[i];
  float4 r; r.x = x.x+y.x; r.y = x.y+y.y; r.z = x.z+y.z; r.w = x.w+y.w;
  o[i] = r;
}

// ---------------------------------------------------------------- restormer channel attention, 16x16 per (b,h)
__global__ __launch_bounds__(256) void k_rattn(const float* __restrict__ qkv, const float* __restrict__ temp,
                                               float* __restrict__ out){
  int blk = blockIdx.x; int b = blk >> 2, h = blk & 3;
  int t = threadIdx.x;
  __shared__ float red[32][9];
  __shared__ float norms[32];
  __shared__ float attn[16][17];
  { // norms of 16 q-rows and 16 k-rows
    int r = t >> 3, ck = t & 7;
    int ch = (r < 16) ? (h*16 + r) : (64 + h*16 + (r-16));
    const float* base = qkv + ((size_t)b*192 + ch)*NHW + ck*512;
    float ss = 0.f;
    for (int i = 0; i < 512; i += 4){
      float4 v = *(const float4*)(base + i);
      ss += v.x*v.x + v.y*v.y + v.z*v.z + v.w*v.w;
    }
    red[r][ck] = ss;
  }
  __syncthreads();
  if (t < 32){
    float s2 = 0.f;
    #pragma unroll
    for (int j = 0; j < 8; ++j) s2 += red[t][j];
    norms[t] = fmaxf(sqrtf(s2), 1e-12f);
  }
  __syncthreads();
  { // 16x16 energy
    int rq = t >> 4, rk = t & 15;
    const float* bq = qkv + ((size_t)b*192 + h*16 + rq)*NHW;
    const float* bk = qkv + ((size_t)b*192 + 64 + h*16 + rk)*NHW;
    float dot = 0.f;
    for (int i = 0; i < NHW; i += 4){
      float4 a = *(const float4*)(bq + i);
      float4 c = *(const float4*)(bk + i);
      dot += a.x*c.x + a.y*c.y + a.z*c.z + a.w*c.w;
    }
    attn[rq][rk] = dot/(norms[rq]*norms[16+rk]) * temp[h];
  }
  __syncthreads();
  if (t < 16){
    float mm = -1e30f;
    #pragma unroll
    for (int k = 0; k < 16; ++k) mm = fmaxf(mm, attn[t][k]);
    float ss = 0.f; float e[16];
    #pragma unroll
    for (int k = 0; k < 16; ++k){ e[k] = __expf(attn[t][k]-mm); ss += e[k]; }
    float is = 1.f/ss;
    #pragma unroll
    for (int k = 0; k < 16; ++k) attn[t][k] = e[k]*is;
  }
  __syncthreads();
  { // out[rq][n] = sum_rk attn * v
    const float* vb = qkv + ((size_t)b*192 + 128 + h*16)*NHW;
    float* ob = out + ((size_t)b*64 + h*16)*NHW;
    for (int rqg = 0; rqg < 4; ++rqg){
      float aw0[16], aw1[16], aw2[16], aw3[16];
      #pragma unroll
      for (int rk = 0; rk < 16; ++rk){
        aw0[rk] = attn[rqg*4+0][rk]; aw1[rk] = attn[rqg*4+1][rk];
        aw2[rk] = attn[rqg*4+2][rk]; aw3[rk] = attn[rqg*4+3][rk];
      }
      for (int n = t; n < NHW; n += 256){
        float o0=0,o1=0,o2=0,o3=0;
        #pragma unroll
        for (int rk = 0; rk < 16; ++rk){
          float vv = vb[rk*NHW + n];
          o0 += aw0[rk]*vv; o1 += aw1[rk]*vv; o2 += aw2[rk]*vv; o3 += aw3[rk]*vv;
        }
        ob[(rqg*4+0)*NHW + n] = o0; ob[(rqg*4+1)*NHW + n] = o1;
        ob[(rqg*4+2)*NHW + n] = o2; ob[(rqg*4+3)*NHW + n] = o3;
      }
    }
  }
}

// ================================================================ host
extern "C" void kernel_launch(void* const* d_in, const int* in_sizes, int n_in,
                              void* d_out, int out_size, void* d_ws, size_t ws_size,
                              hipStream_t stream){
  const float* hsi_f0     = (const float*)d_in[0];
  const float* msi_f0     = (const float*)d_in[1];
  const float* hsi_fi     = (const float*)d_in[2];
  const float* msi_fi     = (const float*)d_in[3];
  const float* sp_mlp_w   = (const float*)d_in[4];
  const float* sp_mlp_b   = (const float*)d_in[5];
  const float* spe_mlp_w  = (const float*)d_in[6];
  const float* spe_mlp_b  = (const float*)d_in[7];
  const float* spa_dw_w   = (const float*)d_in[8];
  const float* spa_dw_b   = (const float*)d_in[9];
  const float* spa_pw_w   = (const float*)d_in[10];
  const float* spa_pw_b   = (const float*)d_in[11];
  const float* spe_dw_w   = (const float*)d_in[12];
  const float* spe_dw_b   = (const float*)d_in[13];
  const float* spe_pw_w   = (const float*)d_in[14];
  const float* spe_pw_b   = (const float*)d_in[15];
  const float* sb_q_w     = (const float*)d_in[16];
  const float* sb_q_b     = (const float*)d_in[17];
  const float* sb_k_w     = (const float*)d_in[18];
  const float* sb_k_b     = (const float*)d_in[19];
  const float* sb_v_w     = (const float*)d_in[20];
  const float* sb_v_b     = (const float*)d_in[21];
  const float* sb_o_w     = (const float*)d_in[22];
  const float* sb_o_b     = (const float*)d_in[23];
  const float* sb_norm2_w = (const float*)d_in[24];
  const float* sb_ffn_in_w  = (const float*)d_in[25];
  const float* sb_ffn_dw_w  = (const float*)d_in[26];
  const float* sb_ffn_out_w = (const float*)d_in[27];
  const float* rb_norm1_w = (const float*)d_in[28];
  const float* rb_temp    = (const float*)d_in[29];
  const float* rb_qkv_w   = (const float*)d_in[30];
  const float* rb_qkv_dw_w= (const float*)d_in[31];
  const float* rb_proj_w  = (const float*)d_in[32];
  const float* rb_norm2_w = (const float*)d_in[33];
  const float* rb_ffn_in_w  = (const float*)d_in[34];
  const float* rb_ffn_dw_w  = (const float*)d_in[35];
  const float* rb_ffn_out_w = (const float*)d_in[36];

  float* W   = (float*)d_ws;
  float* Hb  = W;                 // hsi branch output      [B][64][HW]
  float* Mb  = W + (size_t)SZ;    // msi branch output
  float* Xb  = W + (size_t)2*SZ;  // x1
  float* Yb  = W + (size_t)3*SZ;  // y
  float* T1  = W + (size_t)4*SZ;
  float* T2  = W + (size_t)5*SZ;
  float* T3  = W + (size_t)6*SZ;
  float* QKV = T1;                // 3*SZ contiguous (T1..T3) for restormer qkv
  float* TB  = W + (size_t)7*SZ;  // 2*SZ (128-ch ffn buffer / misc)
  float* TB2 = W + (size_t)9*SZ;  // 3*SZ (192-ch pre-dw qkv)
  float* mxb = W + (size_t)12*SZ;       // 128
  float* speb= mxb + 128;               // 128
  float* cmb = speb + 128;              // 8192
  // total: 12*SZ + 8448 floats ~= 25.2 MB

  float* outf = (float*)d_out;

  // scores
  k_max_hw  <<<NB*NC, 256, 0, stream>>>(hsi_fi, mxb);
  k_spe_score<<<1, 128, 0, stream>>>(mxb, spe_mlp_w, spe_mlp_b, speb);
  k_chmean  <<<NPIX/256, 256, 0, stream>>>(msi_fi, cmb);
  // hsi branch
  k_dw3<<<SZ/256, 256, 0, stream>>>(hsi_f0, spe_dw_w, spe_dw_b, speb, nullptr, nullptr, nullptr, T1);
  k_pw<<<dim3(NPIX/64,1), 256, 0, stream>>>(T1, spe_pw_w, spe_pw_b, nullptr, nullptr, Hb, 64);
  // msi branch
  k_dw3<<<SZ/256, 256, 0, stream>>>(msi_f0, spa_dw_w, spa_dw_b, nullptr, cmb, sp_mlp_w, sp_mlp_b, T1);
  k_pw<<<dim3(NPIX/64,1), 256, 0, stream>>>(T1, spa_pw_w, spa_pw_b, nullptr, nullptr, Mb, 64);
  // cross-attention Q,K,V
  k_pw<<<dim3(NPIX/64,1), 256, 0, stream>>>(Mb, sb_q_w, sb_q_b, nullptr, nullptr, T1, 64);
  k_pw<<<dim3(NPIX/64,1), 256, 0, stream>>>(Hb, sb_k_w, sb_k_b, nullptr, nullptr, T2, 64);
  k_pw<<<dim3(NPIX/64,1), 256, 0, stream>>>(Hb, sb_v_w, sb_v_b, nullptr, nullptr, T3, 64);
  k_flash<<<1024, 256, 0, stream>>>(T1, T2, T3, TB);
  k_pw<<<dim3(NPIX/64,1), 256, 0, stream>>>(TB, sb_o_w, sb_o_b, Mb, nullptr, Xb, 64);  // +msi residual
  // SpectralBlock FFN
  k_ln<<<NPIX/256, 256, 0, stream>>>(Xb, sb_norm2_w, T1);
  k_pw<<<dim3(NPIX/64,2), 256, 0, stream>>>(T1, sb_ffn_in_w, nullptr, nullptr, nullptr, TB, 128);
  k_dwgate<<<SZ/256, 256, 0, stream>>>(TB, sb_ffn_dw_w, T1);
  k_pw<<<dim3(NPIX/64,1), 256, 0, stream>>>(T1, sb_ffn_out_w, nullptr, Xb, nullptr, Xb, 64);
  // RestormerBlock
  k_add4<<<SZ/1024, 256, 0, stream>>>((const float4*)Hb, (const float4*)Mb, (float4*)Yb);
  k_ln<<<NPIX/256, 256, 0, stream>>>(Yb, rb_norm1_w, T1);
  k_pw<<<dim3(NPIX/64,3), 256, 0, stream>>>(T1, rb_qkv_w, nullptr, nullptr, nullptr, TB2, 192);
  k_dw192<<<3*SZ/256, 256, 0, stream>>>(TB2, rb_qkv_dw_w, QKV);
  k_rattn<<<NB*4, 256, 0, stream>>>(QKV, rb_temp, TB);
  k_pw<<<dim3(NPIX/64,1), 256, 0, stream>>>(TB, rb_proj_w, nullptr, Yb, nullptr, Yb, 64);
  // Restormer FFN + final combine: out = x1 + (y + ffn(ln(y)))
  k_ln<<<NPIX/256, 256, 0, stream>>>(Yb, rb_norm2_w, T1);
  k_pw<<<dim3(NPIX/64,2), 256, 0, stream>>>(T1, rb_ffn_in_w, nullptr, nullptr, nullptr, TB, 128);
  k_dwgate<<<SZ/256, 256, 0, stream>>>(TB, rb_ffn_dw_w, T1);
  k_pw<<<dim3(NPIX/64,1), 256, 0, stream>>>(T1, rb_ffn_out_w, nullptr, Xb, Yb, outf, 64);
}

// Round 4
// 960.787 us; speedup vs baseline: 1.0537x; 1.0537x over previous
//
#include <hip/hip_runtime.h>

#define NB 2
#define NC 64
#define NHW 4096
#define NPIX (NB*NHW)          // 8192
#define SZ   (NB*NC*NHW)       // 524288 floats per 64-ch fp32 tensor

__device__ __forceinline__ float clamp01(float v){ return fminf(fmaxf(v, 0.f), 1.f); }

// ---------------------------------------------------------------- reductions
__global__ __launch_bounds__(256) void k_max_hw(const float* __restrict__ in, float* __restrict__ mx){
  int bc = blockIdx.x; int t = threadIdx.x;
  const float* p = in + (size_t)bc*NHW;
  float m = -1e30f;
  for (int n = t; n < NHW; n += 256) m = fmaxf(m, p[n]);
  #pragma unroll
  for (int off = 32; off; off >>= 1) m = fmaxf(m, __shfl_xor(m, off));
  __shared__ float sm[4];
  if ((t & 63) == 0) sm[t >> 6] = m;
  __syncthreads();
  if (t == 0) mx[bc] = fmaxf(fmaxf(sm[0], sm[1]), fmaxf(sm[2], sm[3]));
}

__global__ void k_spe_score(const float* __restrict__ mx, const float* __restrict__ w,
                            const float* __restrict__ bias, float* __restrict__ out){
  int t = threadIdx.x; if (t >= 128) return;
  int b = t >> 6, o = t & 63;
  float acc = bias[o];
  const float* m = mx + b*64;
  for (int i = 0; i < 64; ++i) acc += w[o*64 + i] * m[i];
  out[t] = clamp01(acc);   // relu6 then clip(-1,1) == clamp to [0,1]
}

__global__ __launch_bounds__(256) void k_chmean(const float* __restrict__ in, float* __restrict__ out){
  int p = blockIdx.x*256 + threadIdx.x;         // 0..8191
  int b = p >> 12, n = p & 4095;
  const float* base = in + (size_t)b*NC*NHW + n;
  float s = 0.f;
  #pragma unroll
  for (int c = 0; c < 64; ++c) s += base[c*NHW];
  out[p] = s * (1.0f/64.0f);
}

// ---------------------------------------------------------------- depthwise 3x3 + score adds
__global__ __launch_bounds__(256) void k_dw3(const float* __restrict__ in, const float* __restrict__ w,
    const float* __restrict__ bias, const float* __restrict__ add_bc, const float* __restrict__ chmean,
    const float* __restrict__ spw, const float* __restrict__ spb, float* __restrict__ out){
  int g = blockIdx.x*256 + threadIdx.x;         // B*64*4096
  int pix = g & 4095; int c = (g >> 12) & 63; int b = g >> 18;
  int y = pix >> 6, x = pix & 63;
  const float* base = in + (size_t)(b*64 + c)*NHW;
  float wf[9];
  #pragma unroll
  for (int i = 0; i < 9; ++i) wf[i] = w[c*9 + i];
  float acc = 0.f;
  #pragma unroll
  for (int ky = -1; ky <= 1; ++ky){
    int yy = y + ky; if ((unsigned)yy >= 64u) continue;
    #pragma unroll
    for (int kx = -1; kx <= 1; ++kx){
      int xx = x + kx; if ((unsigned)xx >= 64u) continue;
      acc += base[yy*64 + xx] * wf[(ky+1)*3 + (kx+1)];
    }
  }
  acc += bias[c];
  if (add_bc) acc += add_bc[b*64 + c];
  if (chmean){
    float z = spw[c] * chmean[b*4096 + pix] + spb[c];
    acc += clamp01(z);
  }
  out[g] = acc;
}

// ---------------------------------------------------------------- pointwise conv (64 -> OC), LDS block GEMM
// optional fused bias-free LayerNorm on input (lnw != nullptr):
//   out = (sum_i w[o][i]*lnw[i]*x[i][n]) * invsigma[n] + bias + r1 + r2
// grid: (NPIX/64, OC/64); block 256. Per block: 64 out-ch x 64 pixels.
__global__ __launch_bounds__(256) void k_pw(const float* __restrict__ in, const float* __restrict__ w,
    const float* __restrict__ bias, const float* __restrict__ lnw,
    const float* __restrict__ r1, const float* __restrict__ r2,
    float* __restrict__ outf, int OC){
  __shared__ __align__(16) float Xs[64][64];
  __shared__ __align__(16) float Wt[64][64];    // [i][o]
  __shared__ float psum[4][64], psqs[4][64];
  __shared__ float invs[64];
  int t = threadIdx.x;
  int ptile = blockIdx.x; int oc0 = blockIdx.y*64;
  int b = ptile >> 6; int n0 = (ptile & 63)*64;
  const float* inb = in + (size_t)b*64*NHW;
  float ps = 0.f, pss = 0.f;
  #pragma unroll
  for (int k = 0; k < 16; ++k){
    int idx = k*256 + t; int i = idx >> 6, n = idx & 63;
    float v = inb[i*NHW + n0 + n];
    Xs[i][n] = v;
    ps += v; pss += v*v;
  }
  if (lnw){ psum[t>>6][t&63] = ps; psqs[t>>6][t&63] = pss; }
  #pragma unroll
  for (int k = 0; k < 16; ++k){
    int idx = k*256 + t; int o = idx & 63, i = idx >> 6;
    float wv = w[(oc0 + o)*64 + i];
    if (lnw) wv *= lnw[i];
    Wt[i][o] = wv;
  }
  __syncthreads();
  if (lnw){
    if (t < 64){
      float s1 = psum[0][t]+psum[1][t]+psum[2][t]+psum[3][t];
      float s2 = psqs[0][t]+psqs[1][t]+psqs[2][t]+psqs[3][t];
      float mu = s1*(1.0f/64.0f);
      float var = s2*(1.0f/64.0f) - mu*mu;
      invs[t] = rsqrtf(fmaxf(var, 0.f) + 1e-5f);
    }
    __syncthreads();
  }
  int tn = t & 15, to = t >> 4;
  float a00=0,a01=0,a02=0,a03=0, a10=0,a11=0,a12=0,a13=0;
  float a20=0,a21=0,a22=0,a23=0, a30=0,a31=0,a32=0,a33=0;
  #pragma unroll
  for (int i = 0; i < 64; ++i){
    const float4 xv = *(const float4*)&Xs[i][tn*4];
    const float4 wv = *(const float4*)&Wt[i][to*4];
    a00 += wv.x*xv.x; a01 += wv.x*xv.y; a02 += wv.x*xv.z; a03 += wv.x*xv.w;
    a10 += wv.y*xv.x; a11 += wv.y*xv.y; a12 += wv.y*xv.z; a13 += wv.y*xv.w;
    a20 += wv.z*xv.x; a21 += wv.z*xv.y; a22 += wv.z*xv.z; a23 += wv.z*xv.w;
    a30 += wv.w*xv.x; a31 += wv.w*xv.y; a32 += wv.w*xv.z; a33 += wv.w*xv.w;
  }
  float s0 = 1.f, s1 = 1.f, s2 = 1.f, s3 = 1.f;
  if (lnw){ s0 = invs[tn*4+0]; s1 = invs[tn*4+1]; s2 = invs[tn*4+2]; s3 = invs[tn*4+3]; }
  float accs[4][4] = {{a00,a01,a02,a03},{a10,a11,a12,a13},{a20,a21,a22,a23},{a30,a31,a32,a33}};
  #pragma unroll
  for (int oo = 0; oo < 4; ++oo){
    int o = oc0 + to*4 + oo;
    float bv = bias ? bias[o] : 0.f;
    size_t obase = ((size_t)b*OC + o)*NHW + n0 + tn*4;
    float v0 = accs[oo][0]*s0+bv, v1 = accs[oo][1]*s1+bv, v2 = accs[oo][2]*s2+bv, v3 = accs[oo][3]*s3+bv;
    if (r1){ v0 += r1[obase+0]; v1 += r1[obase+1]; v2 += r1[obase+2]; v3 += r1[obase+3]; }
    if (r2){ v0 += r2[obase+0]; v1 += r2[obase+1]; v2 += r2[obase+2]; v3 += r2[obase+3]; }
    float4 vv; vv.x=v0; vv.y=v1; vv.z=v2; vv.w=v3;
    *(float4*)(outf + obase) = vv;
  }
}

// ---------------------------------------------------------------- flash cross-attention, hd=16, n=4096
// grid: B*HEADS*(4096/128)=256 blocks; block 256 = 32 q-groups x 8 key-splits.
// Each thread: 4 queries x (32 keys per 256-key tile, via 4 iters of 8 keys).
__global__ __launch_bounds__(256) void k_flash(const float* __restrict__ Q, const float* __restrict__ K,
                                               const float* __restrict__ V, float* __restrict__ O){
  __shared__ __align__(16) float Ks[16][256];
  __shared__ __align__(16) float Vs[16][256];
  int blk = blockIdx.x;
  int qt = blk & 31; int bh = blk >> 5;           // bh in 0..7
  size_t cbase = (size_t)bh*16*NHW;               // channel base (b*64+h*16)*NHW
  int t = threadIdx.x;
  int s = t & 7, qg = t >> 3;
  int q0 = qt*128 + qg*4;
  float qv[4][16];
  #pragma unroll
  for (int qq = 0; qq < 4; ++qq)
    #pragma unroll
    for (int d = 0; d < 16; ++d)
      qv[qq][d] = Q[cbase + d*NHW + q0 + qq] * 0.25f;   // fold 1/sqrt(16)
  float m[4], l[4], acc[4][16];
  #pragma unroll
  for (int qq = 0; qq < 4; ++qq){
    m[qq] = -1e30f; l[qq] = 0.f;
    #pragma unroll
    for (int d = 0; d < 16; ++d) acc[qq][d] = 0.f;
  }
  for (int kt = 0; kt < 16; ++kt){
    __syncthreads();
    #pragma unroll
    for (int d = 0; d < 16; ++d){
      Ks[d][t] = K[cbase + d*NHW + kt*256 + t];
      Vs[d][t] = V[cbase + d*NHW + kt*256 + t];
    }
    __syncthreads();
    #pragma unroll
    for (int j = 0; j < 4; ++j){
      int kk = j*64 + s*8;
      float sc[4][8];
      #pragma unroll
      for (int qq = 0; qq < 4; ++qq)
        #pragma unroll
        for (int e = 0; e < 8; ++e) sc[qq][e] = 0.f;
      #pragma unroll
      for (int d = 0; d < 16; ++d){
        const float4 ka = *(const float4*)&Ks[d][kk];
        const float4 kb = *(const float4*)&Ks[d][kk+4];
        #pragma unroll
        for (int qq = 0; qq < 4; ++qq){
          float qd = qv[qq][d];
          sc[qq][0] += qd*ka.x; sc[qq][1] += qd*ka.y; sc[qq][2] += qd*ka.z; sc[qq][3] += qd*ka.w;
          sc[qq][4] += qd*kb.x; sc[qq][5] += qd*kb.y; sc[qq][6] += qd*kb.z; sc[qq][7] += qd*kb.w;
        }
      }
      #pragma unroll
      for (int qq = 0; qq < 4; ++qq){
        float m8 = fmaxf(fmaxf(fmaxf(sc[qq][0],sc[qq][1]),fmaxf(sc[qq][2],sc[qq][3])),
                         fmaxf(fmaxf(sc[qq][4],sc[qq][5]),fmaxf(sc[qq][6],sc[qq][7])));
        float mn = fmaxf(m[qq], m8);
        float f  = __expf(m[qq] - mn);
        float ssum = 0.f;
        #pragma unroll
        for (int e = 0; e < 8; ++e){ sc[qq][e] = __expf(sc[qq][e]-mn); ssum += sc[qq][e]; }
        l[qq] = l[qq]*f + ssum;
        m[qq] = mn;
        #pragma unroll
        for (int d = 0; d < 16; ++d) acc[qq][d] *= f;
      }
      #pragma unroll
      for (int d = 0; d < 16; ++d){
        const float4 va = *(const float4*)&Vs[d][kk];
        const float4 vb = *(const float4*)&Vs[d][kk+4];
        #pragma unroll
        for (int qq = 0; qq < 4; ++qq){
          acc[qq][d] += sc[qq][0]*va.x + sc[qq][1]*va.y + sc[qq][2]*va.z + sc[qq][3]*va.w
                      + sc[qq][4]*vb.x + sc[qq][5]*vb.y + sc[qq][6]*vb.z + sc[qq][7]*vb.w;
        }
      }
    }
  }
  // merge 8 key-splits (lanes t&7)
  #pragma unroll
  for (int off = 1; off <= 4; off <<= 1){
    #pragma unroll
    for (int qq = 0; qq < 4; ++qq){
      float mo = __shfl_xor(m[qq], off);
      float lo = __shfl_xor(l[qq], off);
      float mn = fmaxf(m[qq], mo);
      float fa = __expf(m[qq] - mn), fb = __expf(mo - mn);
      l[qq] = l[qq]*fa + lo*fb;
      #pragma unroll
      for (int d = 0; d < 16; ++d){
        float ao = __shfl_xor(acc[qq][d], off);
        acc[qq][d] = acc[qq][d]*fa + ao*fb;
      }
      m[qq] = mn;
    }
  }
  // write normalized output via LDS transpose for coalesced stores
  __syncthreads();
  float* Os = &Ks[0][0];                    // 16 x 128 floats
  if (s == 0){
    #pragma unroll
    for (int qq = 0; qq < 4; ++qq){
      float inv = 1.0f / l[qq];
      #pragma unroll
      for (int d = 0; d < 16; ++d) Os[d*128 + qg*4 + qq] = acc[qq][d]*inv;
    }
  }
  __syncthreads();
  #pragma unroll
  for (int r = 0; r < 2; ++r){
    int idx = r*1024 + t*4;
    int d = idx >> 7, n = idx & 127;
    *(float4*)(O + cbase + d*NHW + qt*128 + n) = *(const float4*)&Os[idx];
  }
}

// ---------------------------------------------------------------- FFN dw3x3 + chunk + gelu gate (128->64)
__global__ __launch_bounds__(256) void k_dwgate(const float* __restrict__ in, const float* __restrict__ w,
                                                float* __restrict__ out){
  int g = blockIdx.x*256 + threadIdx.x;         // B*64*4096
  int pix = g & 4095; int c = (g >> 12) & 63; int b = g >> 18;
  int y = pix >> 6, x = pix & 63;
  const float* p1 = in + ((size_t)b*128 + c)*NHW;
  const float* p2 = in + ((size_t)b*128 + 64 + c)*NHW;
  float w1[9], w2[9];
  #pragma unroll
  for (int i = 0; i < 9; ++i){ w1[i] = w[c*9+i]; w2[i] = w[(64+c)*9+i]; }
  float a = 0.f, bb = 0.f;
  #pragma unroll
  for (int ky = -1; ky <= 1; ++ky){
    int yy = y + ky; if ((unsigned)yy >= 64u) continue;
    #pragma unroll
    for (int kx = -1; kx <= 1; ++kx){
      int xx = x + kx; if ((unsigned)xx >= 64u) continue;
      int off = yy*64 + xx; int wi = (ky+1)*3 + (kx+1);
      a  += p1[off]*w1[wi];
      bb += p2[off]*w2[wi];
    }
  }
  float gl = 0.5f*a*(1.0f + erff(a*0.70710678118654752f));   // exact gelu
  out[g] = gl*bb;
}

// ---------------------------------------------------------------- dw3x3 on 192 channels (restormer qkv)
__global__ __launch_bounds__(256) void k_dw192(const float* __restrict__ in, const float* __restrict__ w,
                                               float* __restrict__ out){
  int g = blockIdx.x*256 + threadIdx.x;         // B*192*4096
  int pix = g & 4095; int bc = g >> 12; int c = bc % 192;
  int y = pix >> 6, x = pix & 63;
  const float* p = in + (size_t)bc*NHW;
  float wf[9];
  #pragma unroll
  for (int i = 0; i < 9; ++i) wf[i] = w[c*9+i];
  float acc = 0.f;
  #pragma unroll
  for (int ky = -1; ky <= 1; ++ky){
    int yy = y + ky; if ((unsigned)yy >= 64u) continue;
    #pragma unroll
    for (int kx = -1; kx <= 1; ++kx){
      int xx = x + kx; if ((unsigned)xx >= 64u) continue;
      acc += p[yy*64 + xx]*wf[(ky+1)*3 + (kx+1)];
    }
  }
  out[g] = acc;
}

// ---------------------------------------------------------------- elementwise add (float4)
__global__ __launch_bounds__(256) void k_add4(const float4* __restrict__ a, const float4* __restrict__ b,
                                              float4* __restrict__ o){
  int i = blockIdx.x*256 + threadIdx.x;
  float4 x = a[i], y = b[i];
  float4 r; r.x = x.x+y.x; r.y = x.y+y.y; r.z = x.z+y.z; r.w = x.w+y.w;
  o[i] = r;
}

// ---------------------------------------------------------------- restormer channel attention, 16x16 per (b,h)
__global__ __launch_bounds__(256) void k_rattn(const float* __restrict__ qkv, const float* __restrict__ temp,
                                               float* __restrict__ out){
  int blk = blockIdx.x; int b = blk >> 2, h = blk & 3;
  int t = threadIdx.x;
  __shared__ float red[32][9];
  __shared__ float norms[32];
  __shared__ float attn[16][17];
  { // norms of 16 q-rows and 16 k-rows
    int r = t >> 3, ck = t & 7;
    int ch = (r < 16) ? (h*16 + r) : (64 + h*16 + (r-16));
    const float* base = qkv + ((size_t)b*192 + ch)*NHW + ck*512;
    float ss = 0.f;
    for (int i = 0; i < 512; i += 4){
      float4 v = *(const float4*)(base + i);
      ss += v.x*v.x + v.y*v.y + v.z*v.z + v.w*v.w;
    }
    red[r][ck] = ss;
  }
  __syncthreads();
  if (t < 32){
    float s2 = 0.f;
    #pragma unroll
    for (int j = 0; j < 8; ++j) s2 += red[t][j];
    norms[t] = fmaxf(sqrtf(s2), 1e-12f);
  }
  __syncthreads();
  { // 16x16 energy
    int rq = t >> 4, rk = t & 15;
    const float* bq = qkv + ((size_t)b*192 + h*16 + rq)*NHW;
    const float* bk = qkv + ((size_t)b*192 + 64 + h*16 + rk)*NHW;
    float dot = 0.f;
    for (int i = 0; i < NHW; i += 4){
      float4 a = *(const float4*)(bq + i);
      float4 c = *(const float4*)(bk + i);
      dot += a.x*c.x + a.y*c.y + a.z*c.z + a.w*c.w;
    }
    attn[rq][rk] = dot/(norms[rq]*norms[16+rk]) * temp[h];
  }
  __syncthreads();
  if (t < 16){
    float mm = -1e30f;
    #pragma unroll
    for (int k = 0; k < 16; ++k) mm = fmaxf(mm, attn[t][k]);
    float ss = 0.f; float e[16];
    #pragma unroll
    for (int k = 0; k < 16; ++k){ e[k] = __expf(attn[t][k]-mm); ss += e[k]; }
    float is = 1.f/ss;
    #pragma unroll
    for (int k = 0; k < 16; ++k) attn[t][k] = e[k]*is;
  }
  __syncthreads();
  { // out[rq][n] = sum_rk attn * v
    const float* vb = qkv + ((size_t)b*192 + 128 + h*16)*NHW;
    float* ob = out + ((size_t)b*64 + h*16)*NHW;
    for (int rqg = 0; rqg < 4; ++rqg){
      float aw0[16], aw1[16], aw2[16], aw3[16];
      #pragma unroll
      for (int rk = 0; rk < 16; ++rk){
        aw0[rk] = attn[rqg*4+0][rk]; aw1[rk] = attn[rqg*4+1][rk];
        aw2[rk] = attn[rqg*4+2][rk]; aw3[rk] = attn[rqg*4+3][rk];
      }
      for (int n = t; n < NHW; n += 256){
        float o0=0,o1=0,o2=0,o3=0;
        #pragma unroll
        for (int rk = 0; rk < 16; ++rk){
          float vv = vb[rk*NHW + n];
          o0 += aw0[rk]*vv; o1 += aw1[rk]*vv; o2 += aw2[rk]*vv; o3 += aw3[rk]*vv;
        }
        ob[(rqg*4+0)*NHW + n] = o0; ob[(rqg*4+1)*NHW + n] = o1;
        ob[(rqg*4+2)*NHW + n] = o2; ob[(rqg*4+3)*NHW + n] = o3;
      }
    }
  }
}

// ================================================================ host
extern "C" void kernel_launch(void* const* d_in, const int* in_sizes, int n_in,
                              void* d_out, int out_size, void* d_ws, size_t ws_size,
                              hipStream_t stream){
  const float* hsi_f0     = (const float*)d_in[0];
  const float* msi_f0     = (const float*)d_in[1];
  const float* hsi_fi     = (const float*)d_in[2];
  const float* msi_fi     = (const float*)d_in[3];
  const float* sp_mlp_w   = (const float*)d_in[4];
  const float* sp_mlp_b   = (const float*)d_in[5];
  const float* spe_mlp_w  = (const float*)d_in[6];
  const float* spe_mlp_b  = (const float*)d_in[7];
  const float* spa_dw_w   = (const float*)d_in[8];
  const float* spa_dw_b   = (const float*)d_in[9];
  const float* spa_pw_w   = (const float*)d_in[10];
  const float* spa_pw_b   = (const float*)d_in[11];
  const float* spe_dw_w   = (const float*)d_in[12];
  const float* spe_dw_b   = (const float*)d_in[13];
  const float* spe_pw_w   = (const float*)d_in[14];
  const float* spe_pw_b   = (const float*)d_in[15];
  const float* sb_q_w     = (const float*)d_in[16];
  const float* sb_q_b     = (const float*)d_in[17];
  const float* sb_k_w     = (const float*)d_in[18];
  const float* sb_k_b     = (const float*)d_in[19];
  const float* sb_v_w     = (const float*)d_in[20];
  const float* sb_v_b     = (const float*)d_in[21];
  const float* sb_o_w     = (const float*)d_in[22];
  const float* sb_o_b     = (const float*)d_in[23];
  const float* sb_norm2_w = (const float*)d_in[24];
  const float* sb_ffn_in_w  = (const float*)d_in[25];
  const float* sb_ffn_dw_w  = (const float*)d_in[26];
  const float* sb_ffn_out_w = (const float*)d_in[27];
  const float* rb_norm1_w = (const float*)d_in[28];
  const float* rb_temp    = (const float*)d_in[29];
  const float* rb_qkv_w   = (const float*)d_in[30];
  const float* rb_qkv_dw_w= (const float*)d_in[31];
  const float* rb_proj_w  = (const float*)d_in[32];
  const float* rb_norm2_w = (const float*)d_in[33];
  const float* rb_ffn_in_w  = (const float*)d_in[34];
  const float* rb_ffn_dw_w  = (const float*)d_in[35];
  const float* rb_ffn_out_w = (const float*)d_in[36];

  float* W   = (float*)d_ws;
  float* Hb  = W;                 // hsi branch output      [B][64][HW]
  float* Mb  = W + (size_t)SZ;    // msi branch output
  float* Xb  = W + (size_t)2*SZ;  // x1
  float* Yb  = W + (size_t)3*SZ;  // y
  float* T1  = W + (size_t)4*SZ;
  float* T2  = W + (size_t)5*SZ;
  float* T3  = W + (size_t)6*SZ;
  float* QKV = T1;                // 3*SZ contiguous (T1..T3) for restormer qkv
  float* TB  = W + (size_t)7*SZ;  // 2*SZ (128-ch ffn buffer / misc)
  float* TB2 = W + (size_t)9*SZ;  // 3*SZ (192-ch pre-dw qkv)
  float* mxb = W + (size_t)12*SZ;       // 128
  float* speb= mxb + 128;               // 128
  float* cmb = speb + 128;              // 8192

  float* outf = (float*)d_out;

  // scores
  k_max_hw  <<<NB*NC, 256, 0, stream>>>(hsi_fi, mxb);
  k_spe_score<<<1, 128, 0, stream>>>(mxb, spe_mlp_w, spe_mlp_b, speb);
  k_chmean  <<<NPIX/256, 256, 0, stream>>>(msi_fi, cmb);
  // hsi branch
  k_dw3<<<SZ/256, 256, 0, stream>>>(hsi_f0, spe_dw_w, spe_dw_b, speb, nullptr, nullptr, nullptr, T1);
  k_pw<<<dim3(NPIX/64,1), 256, 0, stream>>>(T1, spe_pw_w, spe_pw_b, nullptr, nullptr, nullptr, Hb, 64);
  // msi branch
  k_dw3<<<SZ/256, 256, 0, stream>>>(msi_f0, spa_dw_w, spa_dw_b, nullptr, cmb, sp_mlp_w, sp_mlp_b, T1);
  k_pw<<<dim3(NPIX/64,1), 256, 0, stream>>>(T1, spa_pw_w, spa_pw_b, nullptr, nullptr, nullptr, Mb, 64);
  // cross-attention Q,K,V
  k_pw<<<dim3(NPIX/64,1), 256, 0, stream>>>(Mb, sb_q_w, sb_q_b, nullptr, nullptr, nullptr, T1, 64);
  k_pw<<<dim3(NPIX/64,1), 256, 0, stream>>>(Hb, sb_k_w, sb_k_b, nullptr, nullptr, nullptr, T2, 64);
  k_pw<<<dim3(NPIX/64,1), 256, 0, stream>>>(Hb, sb_v_w, sb_v_b, nullptr, nullptr, nullptr, T3, 64);
  k_flash<<<256, 256, 0, stream>>>(T1, T2, T3, TB);
  k_pw<<<dim3(NPIX/64,1), 256, 0, stream>>>(TB, sb_o_w, sb_o_b, nullptr, Mb, nullptr, Xb, 64);  // +msi residual
  // SpectralBlock FFN (LayerNorm fused into the 1x1 conv)
  k_pw<<<dim3(NPIX/64,2), 256, 0, stream>>>(Xb, sb_ffn_in_w, nullptr, sb_norm2_w, nullptr, nullptr, TB, 128);
  k_dwgate<<<SZ/256, 256, 0, stream>>>(TB, sb_ffn_dw_w, T1);
  k_pw<<<dim3(NPIX/64,1), 256, 0, stream>>>(T1, sb_ffn_out_w, nullptr, nullptr, Xb, nullptr, Xb, 64);
  // RestormerBlock
  k_add4<<<SZ/1024, 256, 0, stream>>>((const float4*)Hb, (const float4*)Mb, (float4*)Yb);
  k_pw<<<dim3(NPIX/64,3), 256, 0, stream>>>(Yb, rb_qkv_w, nullptr, rb_norm1_w, nullptr, nullptr, TB2, 192);
  k_dw192<<<3*SZ/256, 256, 0, stream>>>(TB2, rb_qkv_dw_w, QKV);
  k_rattn<<<NB*4, 256, 0, stream>>>(QKV, rb_temp, TB);
  k_pw<<<dim3(NPIX/64,1), 256, 0, stream>>>(TB, rb_proj_w, nullptr, nullptr, Yb, nullptr, Yb, 64);
  // Restormer FFN + final combine: out = x1 + (y + ffn(ln(y)))
  k_pw<<<dim3(NPIX/64,2), 256, 0, stream>>>(Yb, rb_ffn_in_w, nullptr, rb_norm2_w, nullptr, nullptr, TB, 128);
  k_dwgate<<<SZ/256, 256, 0, stream>>>(TB, rb_ffn_dw_w, T1);
  k_pw<<<dim3(NPIX/64,1), 256, 0, stream>>>(T1, rb_ffn_out_w, nullptr, nullptr, Xb, Yb, outf, 64);
}

// Round 5
// 726.095 us; speedup vs baseline: 1.3942x; 1.3232x over previous
//
#include <hip/hip_runtime.h>

#define NB 2
#define NC 64
#define NHW 4096
#define NPIX (NB*NHW)          // 8192
#define SZ   (NB*NC*NHW)       // 524288 floats per 64-ch fp32 tensor

__device__ __forceinline__ float clamp01(float v){ return fminf(fmaxf(v, 0.f), 1.f); }

// ---------------------------------------------------------------- reductions
__global__ __launch_bounds__(256) void k_max_hw(const float* __restrict__ in, float* __restrict__ mx){
  int bc = blockIdx.x; int t = threadIdx.x;
  const float* p = in + (size_t)bc*NHW;
  float m = -1e30f;
  for (int n = t; n < NHW; n += 256) m = fmaxf(m, p[n]);
  #pragma unroll
  for (int off = 32; off; off >>= 1) m = fmaxf(m, __shfl_xor(m, off));
  __shared__ float sm[4];
  if ((t & 63) == 0) sm[t >> 6] = m;
  __syncthreads();
  if (t == 0) mx[bc] = fmaxf(fmaxf(sm[0], sm[1]), fmaxf(sm[2], sm[3]));
}

__global__ void k_spe_score(const float* __restrict__ mx, const float* __restrict__ w,
                            const float* __restrict__ bias, float* __restrict__ out){
  int t = threadIdx.x; if (t >= 128) return;
  int b = t >> 6, o = t & 63;
  float acc = bias[o];
  const float* m = mx + b*64;
  for (int i = 0; i < 64; ++i) acc += w[o*64 + i] * m[i];
  out[t] = clamp01(acc);   // relu6 then clip(-1,1) == clamp to [0,1]
}

__global__ __launch_bounds__(256) void k_chmean(const float* __restrict__ in, float* __restrict__ out){
  int p = blockIdx.x*256 + threadIdx.x;         // 0..8191
  int b = p >> 12, n = p & 4095;
  const float* base = in + (size_t)b*NC*NHW + n;
  float s = 0.f;
  #pragma unroll
  for (int c = 0; c < 64; ++c) s += base[c*NHW];
  out[p] = s * (1.0f/64.0f);
}

// ---------------------------------------------------------------- depthwise 3x3 + score adds
__global__ __launch_bounds__(256) void k_dw3(const float* __restrict__ in, const float* __restrict__ w,
    const float* __restrict__ bias, const float* __restrict__ add_bc, const float* __restrict__ chmean,
    const float* __restrict__ spw, const float* __restrict__ spb, float* __restrict__ out){
  int g = blockIdx.x*256 + threadIdx.x;         // B*64*4096
  int pix = g & 4095; int c = (g >> 12) & 63; int b = g >> 18;
  int y = pix >> 6, x = pix & 63;
  const float* base = in + (size_t)(b*64 + c)*NHW;
  float wf[9];
  #pragma unroll
  for (int i = 0; i < 9; ++i) wf[i] = w[c*9 + i];
  float acc = 0.f;
  #pragma unroll
  for (int ky = -1; ky <= 1; ++ky){
    int yy = y + ky; if ((unsigned)yy >= 64u) continue;
    #pragma unroll
    for (int kx = -1; kx <= 1; ++kx){
      int xx = x + kx; if ((unsigned)xx >= 64u) continue;
      acc += base[yy*64 + xx] * wf[(ky+1)*3 + (kx+1)];
    }
  }
  acc += bias[c];
  if (add_bc) acc += add_bc[b*64 + c];
  if (chmean){
    float z = spw[c] * chmean[b*4096 + pix] + spb[c];
    acc += clamp01(z);
  }
  out[g] = acc;
}

// ---------------------------------------------------------------- pointwise conv (64 -> OC), LDS block GEMM
// optional fused bias-free LayerNorm on input (lnw != nullptr)
__global__ __launch_bounds__(256) void k_pw(const float* __restrict__ in, const float* __restrict__ w,
    const float* __restrict__ bias, const float* __restrict__ lnw,
    const float* __restrict__ r1, const float* __restrict__ r2,
    float* __restrict__ outf, int OC){
  __shared__ __align__(16) float Xs[64][64];
  __shared__ __align__(16) float Wt[64][64];    // [i][o]
  __shared__ float psum[4][64], psqs[4][64];
  __shared__ float invs[64];
  int t = threadIdx.x;
  int ptile = blockIdx.x; int oc0 = blockIdx.y*64;
  int b = ptile >> 6; int n0 = (ptile & 63)*64;
  const float* inb = in + (size_t)b*64*NHW;
  float ps = 0.f, pss = 0.f;
  #pragma unroll
  for (int k = 0; k < 16; ++k){
    int idx = k*256 + t; int i = idx >> 6, n = idx & 63;
    float v = inb[i*NHW + n0 + n];
    Xs[i][n] = v;
    ps += v; pss += v*v;
  }
  if (lnw){ psum[t>>6][t&63] = ps; psqs[t>>6][t&63] = pss; }
  #pragma unroll
  for (int k = 0; k < 16; ++k){
    int idx = k*256 + t; int o = idx & 63, i = idx >> 6;
    float wv = w[(oc0 + o)*64 + i];
    if (lnw) wv *= lnw[i];
    Wt[i][o] = wv;
  }
  __syncthreads();
  if (lnw){
    if (t < 64){
      float s1 = psum[0][t]+psum[1][t]+psum[2][t]+psum[3][t];
      float s2 = psqs[0][t]+psqs[1][t]+psqs[2][t]+psqs[3][t];
      float mu = s1*(1.0f/64.0f);
      float var = s2*(1.0f/64.0f) - mu*mu;
      invs[t] = rsqrtf(fmaxf(var, 0.f) + 1e-5f);
    }
    __syncthreads();
  }
  int tn = t & 15, to = t >> 4;
  float a00=0,a01=0,a02=0,a03=0, a10=0,a11=0,a12=0,a13=0;
  float a20=0,a21=0,a22=0,a23=0, a30=0,a31=0,a32=0,a33=0;
  #pragma unroll
  for (int i = 0; i < 64; ++i){
    const float4 xv = *(const float4*)&Xs[i][tn*4];
    const float4 wv = *(const float4*)&Wt[i][to*4];
    a00 += wv.x*xv.x; a01 += wv.x*xv.y; a02 += wv.x*xv.z; a03 += wv.x*xv.w;
    a10 += wv.y*xv.x; a11 += wv.y*xv.y; a12 += wv.y*xv.z; a13 += wv.y*xv.w;
    a20 += wv.z*xv.x; a21 += wv.z*xv.y; a22 += wv.z*xv.z; a23 += wv.z*xv.w;
    a30 += wv.w*xv.x; a31 += wv.w*xv.y; a32 += wv.w*xv.z; a33 += wv.w*xv.w;
  }
  float s0 = 1.f, s1 = 1.f, s2 = 1.f, s3 = 1.f;
  if (lnw){ s0 = invs[tn*4+0]; s1 = invs[tn*4+1]; s2 = invs[tn*4+2]; s3 = invs[tn*4+3]; }
  float accs[4][4] = {{a00,a01,a02,a03},{a10,a11,a12,a13},{a20,a21,a22,a23},{a30,a31,a32,a33}};
  #pragma unroll
  for (int oo = 0; oo < 4; ++oo){
    int o = oc0 + to*4 + oo;
    float bv = bias ? bias[o] : 0.f;
    size_t obase = ((size_t)b*OC + o)*NHW + n0 + tn*4;
    float v0 = accs[oo][0]*s0+bv, v1 = accs[oo][1]*s1+bv, v2 = accs[oo][2]*s2+bv, v3 = accs[oo][3]*s3+bv;
    if (r1){ v0 += r1[obase+0]; v1 += r1[obase+1]; v2 += r1[obase+2]; v3 += r1[obase+3]; }
    if (r2){ v0 += r2[obase+0]; v1 += r2[obase+1]; v2 += r2[obase+2]; v3 += r2[obase+3]; }
    float4 vv; vv.x=v0; vv.y=v1; vv.z=v2; vv.w=v3;
    *(float4*)(outf + obase) = vv;
  }
}

// ---------------------------------------------------------------- flash cross-attention, hd=16, n=4096
// grid 512 = (qt 0..31) x (bh 0..7) x (chunk 0..1); block 256 = 32 q-groups x 8 key-splits.
// chunk c covers keys [c*2048, (c+1)*2048); partials (m,l,acc16) merged by k_fcomb.
__global__ __launch_bounds__(256) void k_flash(const float* __restrict__ Q, const float* __restrict__ K,
                                               const float* __restrict__ V, float* __restrict__ Pacc,
                                               float* __restrict__ Pm, float* __restrict__ Pl){
  __shared__ __align__(16) float Ks[16][256];
  __shared__ __align__(16) float Vs[16][256];
  int blk = blockIdx.x;
  int qt = blk & 31; int bh = (blk >> 5) & 7; int c = blk >> 8;
  size_t cbase = (size_t)bh*16*NHW;
  int t = threadIdx.x;
  int s = t & 7, qg = t >> 3;
  int q0 = qt*128 + qg*4;
  float qv[4][16];
  #pragma unroll
  for (int qq = 0; qq < 4; ++qq)
    #pragma unroll
    for (int d = 0; d < 16; ++d)
      qv[qq][d] = Q[cbase + d*NHW + q0 + qq] * 0.25f;   // fold 1/sqrt(16)
  float m[4], l[4], acc[4][16];
  #pragma unroll
  for (int qq = 0; qq < 4; ++qq){
    m[qq] = -1e30f; l[qq] = 0.f;
    #pragma unroll
    for (int d = 0; d < 16; ++d) acc[qq][d] = 0.f;
  }
  for (int kt = c*8; kt < c*8 + 8; ++kt){
    __syncthreads();
    { // stage 16x256 K and V tiles: wave w handles rows w*4..w*4+3, float4 per lane
      int wv_ = t >> 6, tx = t & 63;
      #pragma unroll
      for (int r = 0; r < 4; ++r){
        int d = wv_*4 + r; int col = tx*4;
        *(float4*)&Ks[d][col] = *(const float4*)&K[cbase + (size_t)d*NHW + kt*256 + col];
        *(float4*)&Vs[d][col] = *(const float4*)&V[cbase + (size_t)d*NHW + kt*256 + col];
      }
    }
    __syncthreads();
    #pragma unroll
    for (int it = 0; it < 4; ++it){
      int kk = it*64 + s*4;            // +0 and +32: bank slots s*4 -> conflict-free
      float sc[4][8];
      #pragma unroll
      for (int qq = 0; qq < 4; ++qq)
        #pragma unroll
        for (int e = 0; e < 8; ++e) sc[qq][e] = 0.f;
      #pragma unroll
      for (int d = 0; d < 16; ++d){
        const float4 ka = *(const float4*)&Ks[d][kk];
        const float4 kb = *(const float4*)&Ks[d][kk+32];
        #pragma unroll
        for (int qq = 0; qq < 4; ++qq){
          float qd = qv[qq][d];
          sc[qq][0] += qd*ka.x; sc[qq][1] += qd*ka.y; sc[qq][2] += qd*ka.z; sc[qq][3] += qd*ka.w;
          sc[qq][4] += qd*kb.x; sc[qq][5] += qd*kb.y; sc[qq][6] += qd*kb.z; sc[qq][7] += qd*kb.w;
        }
      }
      #pragma unroll
      for (int qq = 0; qq < 4; ++qq){
        float m8 = fmaxf(fmaxf(fmaxf(sc[qq][0],sc[qq][1]),fmaxf(sc[qq][2],sc[qq][3])),
                         fmaxf(fmaxf(sc[qq][4],sc[qq][5]),fmaxf(sc[qq][6],sc[qq][7])));
        float mn = fmaxf(m[qq], m8);
        float f  = __expf(m[qq] - mn);
        float ssum = 0.f;
        #pragma unroll
        for (int e = 0; e < 8; ++e){ sc[qq][e] = __expf(sc[qq][e]-mn); ssum += sc[qq][e]; }
        l[qq] = l[qq]*f + ssum;
        m[qq] = mn;
        #pragma unroll
        for (int d = 0; d < 16; ++d) acc[qq][d] *= f;
      }
      #pragma unroll
      for (int d = 0; d < 16; ++d){
        const float4 va = *(const float4*)&Vs[d][kk];
        const float4 vb = *(const float4*)&Vs[d][kk+32];
        #pragma unroll
        for (int qq = 0; qq < 4; ++qq){
          acc[qq][d] += sc[qq][0]*va.x + sc[qq][1]*va.y + sc[qq][2]*va.z + sc[qq][3]*va.w
                      + sc[qq][4]*vb.x + sc[qq][5]*vb.y + sc[qq][6]*vb.z + sc[qq][7]*vb.w;
        }
      }
    }
  }
  // merge 8 key-splits (lanes t&7)
  #pragma unroll
  for (int off = 1; off <= 4; off <<= 1){
    #pragma unroll
    for (int qq = 0; qq < 4; ++qq){
      float mo = __shfl_xor(m[qq], off);
      float lo = __shfl_xor(l[qq], off);
      float mn = fmaxf(m[qq], mo);
      float fa = __expf(m[qq] - mn), fb = __expf(mo - mn);
      l[qq] = l[qq]*fa + lo*fb;
      #pragma unroll
      for (int d = 0; d < 16; ++d){
        float ao = __shfl_xor(acc[qq][d], off);
        acc[qq][d] = acc[qq][d]*fa + ao*fb;
      }
      m[qq] = mn;
    }
  }
  if (s == 0){
    int pb = c*8 + bh;
    #pragma unroll
    for (int qq = 0; qq < 4; ++qq){
      Pm[(size_t)pb*4096 + q0 + qq] = m[qq];
      Pl[(size_t)pb*4096 + q0 + qq] = l[qq];
      #pragma unroll
      for (int d = 0; d < 16; ++d)
        Pacc[((size_t)pb*16 + d)*4096 + q0 + qq] = acc[qq][d];
    }
  }
}

// combine the 2 key-chunks -> final O  (grid 128, block 256)
__global__ __launch_bounds__(256) void k_fcomb(const float* __restrict__ Pacc, const float* __restrict__ Pm,
                                               const float* __restrict__ Pl, float* __restrict__ O){
  int tid = blockIdx.x*256 + threadIdx.x;       // 0..32767
  int q = tid & 4095; int bh = tid >> 12;
  float m0 = Pm[(size_t)bh*4096 + q],      m1 = Pm[(size_t)(8+bh)*4096 + q];
  float l0 = Pl[(size_t)bh*4096 + q],      l1 = Pl[(size_t)(8+bh)*4096 + q];
  float mn = fmaxf(m0, m1);
  float f0 = __expf(m0 - mn), f1 = __expf(m1 - mn);
  float inv = 1.0f / (l0*f0 + l1*f1);
  size_t cbase = (size_t)bh*16*NHW;
  #pragma unroll
  for (int d = 0; d < 16; ++d){
    float a0 = Pacc[((size_t)bh*16 + d)*4096 + q];
    float a1 = Pacc[((size_t)(8+bh)*16 + d)*4096 + q];
    O[cbase + (size_t)d*NHW + q] = (a0*f0 + a1*f1)*inv;
  }
}

// ---------------------------------------------------------------- FFN dw3x3 + chunk + gelu gate (128->64)
__global__ __launch_bounds__(256) void k_dwgate(const float* __restrict__ in, const float* __restrict__ w,
                                                float* __restrict__ out){
  int g = blockIdx.x*256 + threadIdx.x;         // B*64*4096
  int pix = g & 4095; int c = (g >> 12) & 63; int b = g >> 18;
  int y = pix >> 6, x = pix & 63;
  const float* p1 = in + ((size_t)b*128 + c)*NHW;
  const float* p2 = in + ((size_t)b*128 + 64 + c)*NHW;
  float w1[9], w2[9];
  #pragma unroll
  for (int i = 0; i < 9; ++i){ w1[i] = w[c*9+i]; w2[i] = w[(64+c)*9+i]; }
  float a = 0.f, bb = 0.f;
  #pragma unroll
  for (int ky = -1; ky <= 1; ++ky){
    int yy = y + ky; if ((unsigned)yy >= 64u) continue;
    #pragma unroll
    for (int kx = -1; kx <= 1; ++kx){
      int xx = x + kx; if ((unsigned)xx >= 64u) continue;
      int off = yy*64 + xx; int wi = (ky+1)*3 + (kx+1);
      a  += p1[off]*w1[wi];
      bb += p2[off]*w2[wi];
    }
  }
  float gl = 0.5f*a*(1.0f + erff(a*0.70710678118654752f));   // exact gelu
  out[g] = gl*bb;
}

// ---------------------------------------------------------------- dw3x3 on 192 channels (restormer qkv)
__global__ __launch_bounds__(256) void k_dw192(const float* __restrict__ in, const float* __restrict__ w,
                                               float* __restrict__ out){
  int g = blockIdx.x*256 + threadIdx.x;         // B*192*4096
  int pix = g & 4095; int bc = g >> 12; int c = bc % 192;
  int y = pix >> 6, x = pix & 63;
  const float* p = in + (size_t)bc*NHW;
  float wf[9];
  #pragma unroll
  for (int i = 0; i < 9; ++i) wf[i] = w[c*9+i];
  float acc = 0.f;
  #pragma unroll
  for (int ky = -1; ky <= 1; ++ky){
    int yy = y + ky; if ((unsigned)yy >= 64u) continue;
    #pragma unroll
    for (int kx = -1; kx <= 1; ++kx){
      int xx = x + kx; if ((unsigned)xx >= 64u) continue;
      acc += p[yy*64 + xx]*wf[(ky+1)*3 + (kx+1)];
    }
  }
  out[g] = acc;
}

// ---------------------------------------------------------------- elementwise add (float4)
__global__ __launch_bounds__(256) void k_add4(const float4* __restrict__ a, const float4* __restrict__ b,
                                              float4* __restrict__ o){
  int i = blockIdx.x*256 + threadIdx.x;
  float4 x = a[i], y = b[i];
  float4 r; r.x = x.x+y.x; r.y = x.y+y.y; r.z = x.z+y.z; r.w = x.w+y.w;
  o[i] = r;
}

// ---------------------------------------------------------------- restormer channel attention
// k_rnorm: grid 256 = b*128 + ch (ch 0..63 = q rows, 64..127 = k rows); row L2 norms
__global__ __launch_bounds__(256) void k_rnorm(const float* __restrict__ qkv, float* __restrict__ norms){
  int blk = blockIdx.x; int b = blk >> 7, r = blk & 127;
  int t = threadIdx.x;
  const float* p = qkv + ((size_t)b*192 + r)*NHW;
  float ss = 0.f;
  for (int i = t*4; i < NHW; i += 1024){
    float4 v = *(const float4*)(p + i);
    ss += v.x*v.x + v.y*v.y + v.z*v.z + v.w*v.w;
  }
  #pragma unroll
  for (int off = 32; off; off >>= 1) ss += __shfl_xor(ss, off);
  __shared__ float sm[4];
  if ((t & 63) == 0) sm[t >> 6] = ss;
  __syncthreads();
  if (t == 0) norms[blk] = fmaxf(sqrtf(sm[0]+sm[1]+sm[2]+sm[3]), 1e-12f);
}

// k_rattn2: grid 128 = ((b*4+h)*16 + rq); one output row per block
__global__ __launch_bounds__(256) void k_rattn2(const float* __restrict__ qkv, const float* __restrict__ norms,
                                                const float* __restrict__ temp, float* __restrict__ out){
  int blk = blockIdx.x; int rq = blk & 15, h = (blk >> 4) & 3, b = blk >> 6;
  int t = threadIdx.x;
  const float* bq = qkv + ((size_t)b*192 + h*16 + rq)*NHW;
  const float* bk = qkv + ((size_t)b*192 + 64 + h*16)*NHW;
  float p[16];
  #pragma unroll
  for (int rk = 0; rk < 16; ++rk) p[rk] = 0.f;
  for (int n = t; n < NHW; n += 256){
    float qv = bq[n];
    #pragma unroll
    for (int rk = 0; rk < 16; ++rk) p[rk] += qv * bk[(size_t)rk*NHW + n];
  }
  #pragma unroll
  for (int rk = 0; rk < 16; ++rk)
    #pragma unroll
    for (int off = 32; off; off >>= 1) p[rk] += __shfl_xor(p[rk], off);
  __shared__ float red[4][16];
  if ((t & 63) == 0){
    int wv_ = t >> 6;
    #pragma unroll
    for (int rk = 0; rk < 16; ++rk) red[wv_][rk] = p[rk];
  }
  __syncthreads();
  __shared__ float attn[16];
  if (t == 0){
    float nq = norms[b*128 + h*16 + rq];
    float tp = temp[h];
    float e[16]; float mm = -1e30f;
    #pragma unroll
    for (int rk = 0; rk < 16; ++rk){
      float dot = red[0][rk]+red[1][rk]+red[2][rk]+red[3][rk];
      e[rk] = dot/(nq*norms[b*128 + 64 + h*16 + rk]) * tp;
      mm = fmaxf(mm, e[rk]);
    }
    float ssum = 0.f;
    #pragma unroll
    for (int rk = 0; rk < 16; ++rk){ e[rk] = __expf(e[rk]-mm); ssum += e[rk]; }
    float is = 1.f/ssum;
    #pragma unroll
    for (int rk = 0; rk < 16; ++rk) attn[rk] = e[rk]*is;
  }
  __syncthreads();
  float aw[16];
  #pragma unroll
  for (int rk = 0; rk < 16; ++rk) aw[rk] = attn[rk];
  const float* vb = qkv + ((size_t)b*192 + 128 + h*16)*NHW;
  float* ob = out + ((size_t)b*64 + h*16 + rq)*NHW;
  for (int n = t*4; n < NHW; n += 1024){
    float4 o; o.x = 0.f; o.y = 0.f; o.z = 0.f; o.w = 0.f;
    #pragma unroll
    for (int rk = 0; rk < 16; ++rk){
      float4 v = *(const float4*)(vb + (size_t)rk*NHW + n);
      o.x += aw[rk]*v.x; o.y += aw[rk]*v.y; o.z += aw[rk]*v.z; o.w += aw[rk]*v.w;
    }
    *(float4*)(ob + n) = o;
  }
}

// ================================================================ host
extern "C" void kernel_launch(void* const* d_in, const int* in_sizes, int n_in,
                              void* d_out, int out_size, void* d_ws, size_t ws_size,
                              hipStream_t stream){
  const float* hsi_f0     = (const float*)d_in[0];
  const float* msi_f0     = (const float*)d_in[1];
  const float* hsi_fi     = (const float*)d_in[2];
  const float* msi_fi     = (const float*)d_in[3];
  const float* sp_mlp_w   = (const float*)d_in[4];
  const float* sp_mlp_b   = (const float*)d_in[5];
  const float* spe_mlp_w  = (const float*)d_in[6];
  const float* spe_mlp_b  = (const float*)d_in[7];
  const float* spa_dw_w   = (const float*)d_in[8];
  const float* spa_dw_b   = (const float*)d_in[9];
  const float* spa_pw_w   = (const float*)d_in[10];
  const float* spa_pw_b   = (const float*)d_in[11];
  const float* spe_dw_w   = (const float*)d_in[12];
  const float* spe_dw_b   = (const float*)d_in[13];
  const float* spe_pw_w   = (const float*)d_in[14];
  const float* spe_pw_b   = (const float*)d_in[15];
  const float* sb_q_w     = (const float*)d_in[16];
  const float* sb_q_b     = (const float*)d_in[17];
  const float* sb_k_w     = (const float*)d_in[18];
  const float* sb_k_b     = (const float*)d_in[19];
  const float* sb_v_w     = (const float*)d_in[20];
  const float* sb_v_b     = (const float*)d_in[21];
  const float* sb_o_w     = (const float*)d_in[22];
  const float* sb_o_b     = (const float*)d_in[23];
  const float* sb_norm2_w = (const float*)d_in[24];
  const float* sb_ffn_in_w  = (const float*)d_in[25];
  const float* sb_ffn_dw_w  = (const float*)d_in[26];
  const float* sb_ffn_out_w = (const float*)d_in[27];
  const float* rb_norm1_w = (const float*)d_in[28];
  const float* rb_temp    = (const float*)d_in[29];
  const float* rb_qkv_w   = (const float*)d_in[30];
  const float* rb_qkv_dw_w= (const float*)d_in[31];
  const float* rb_proj_w  = (const float*)d_in[32];
  const float* rb_norm2_w = (const float*)d_in[33];
  const float* rb_ffn_in_w  = (const float*)d_in[34];
  const float* rb_ffn_dw_w  = (const float*)d_in[35];
  const float* rb_ffn_out_w = (const float*)d_in[36];

  float* W   = (float*)d_ws;
  float* Hb  = W;                 // hsi branch output      [B][64][HW]
  float* Mb  = W + (size_t)SZ;    // msi branch output
  float* Xb  = W + (size_t)2*SZ;  // x1
  float* Yb  = W + (size_t)3*SZ;  // y
  float* T1  = W + (size_t)4*SZ;
  float* T2  = W + (size_t)5*SZ;
  float* T3  = W + (size_t)6*SZ;
  float* QKV = T1;                // 3*SZ contiguous (T1..T3) for restormer qkv
  float* TB  = W + (size_t)7*SZ;  // 2*SZ (128-ch ffn buffer / attn out / misc)
  float* TB2 = W + (size_t)9*SZ;  // 3*SZ (192-ch pre-dw qkv; flash partials during flash)
  float* Pacc= TB2;                      // 2*SZ  (flash partial acc)
  float* Pm  = W + (size_t)11*SZ;        // 65536
  float* Pl  = W + (size_t)11*SZ + 65536;// 65536
  float* mxb = W + (size_t)12*SZ;        // 128
  float* speb= mxb + 128;                // 128
  float* cmb = speb + 128;               // 8192
  float* normb = W + (size_t)12*SZ + 9216; // 256

  float* outf = (float*)d_out;

  // scores
  k_max_hw  <<<NB*NC, 256, 0, stream>>>(hsi_fi, mxb);
  k_spe_score<<<1, 128, 0, stream>>>(mxb, spe_mlp_w, spe_mlp_b, speb);
  k_chmean  <<<NPIX/256, 256, 0, stream>>>(msi_fi, cmb);
  // hsi branch
  k_dw3<<<SZ/256, 256, 0, stream>>>(hsi_f0, spe_dw_w, spe_dw_b, speb, nullptr, nullptr, nullptr, T1);
  k_pw<<<dim3(NPIX/64,1), 256, 0, stream>>>(T1, spe_pw_w, spe_pw_b, nullptr, nullptr, nullptr, Hb, 64);
  // msi branch
  k_dw3<<<SZ/256, 256, 0, stream>>>(msi_f0, spa_dw_w, spa_dw_b, nullptr, cmb, sp_mlp_w, sp_mlp_b, T1);
  k_pw<<<dim3(NPIX/64,1), 256, 0, stream>>>(T1, spa_pw_w, spa_pw_b, nullptr, nullptr, nullptr, Mb, 64);
  // cross-attention Q,K,V
  k_pw<<<dim3(NPIX/64,1), 256, 0, stream>>>(Mb, sb_q_w, sb_q_b, nullptr, nullptr, nullptr, T1, 64);
  k_pw<<<dim3(NPIX/64,1), 256, 0, stream>>>(Hb, sb_k_w, sb_k_b, nullptr, nullptr, nullptr, T2, 64);
  k_pw<<<dim3(NPIX/64,1), 256, 0, stream>>>(Hb, sb_v_w, sb_v_b, nullptr, nullptr, nullptr, T3, 64);
  k_flash<<<512, 256, 0, stream>>>(T1, T2, T3, Pacc, Pm, Pl);
  k_fcomb<<<128, 256, 0, stream>>>(Pacc, Pm, Pl, TB);
  k_pw<<<dim3(NPIX/64,1), 256, 0, stream>>>(TB, sb_o_w, sb_o_b, nullptr, Mb, nullptr, Xb, 64);  // +msi residual
  // SpectralBlock FFN (LayerNorm fused into the 1x1 conv)
  k_pw<<<dim3(NPIX/64,2), 256, 0, stream>>>(Xb, sb_ffn_in_w, nullptr, sb_norm2_w, nullptr, nullptr, TB, 128);
  k_dwgate<<<SZ/256, 256, 0, stream>>>(TB, sb_ffn_dw_w, T1);
  k_pw<<<dim3(NPIX/64,1), 256, 0, stream>>>(T1, sb_ffn_out_w, nullptr, nullptr, Xb, nullptr, Xb, 64);
  // RestormerBlock
  k_add4<<<SZ/1024, 256, 0, stream>>>((const float4*)Hb, (const float4*)Mb, (float4*)Yb);
  k_pw<<<dim3(NPIX/64,3), 256, 0, stream>>>(Yb, rb_qkv_w, nullptr, rb_norm1_w, nullptr, nullptr, TB2, 192);
  k_dw192<<<3*SZ/256, 256, 0, stream>>>(TB2, rb_qkv_dw_w, QKV);
  k_rnorm<<<256, 256, 0, stream>>>(QKV, normb);
  k_rattn2<<<128, 256, 0, stream>>>(QKV, normb, rb_temp, TB);
  k_pw<<<dim3(NPIX/64,1), 256, 0, stream>>>(TB, rb_proj_w, nullptr, nullptr, Yb, nullptr, Yb, 64);
  // Restormer FFN + final combine: out = x1 + (y + ffn(ln(y)))
  k_pw<<<dim3(NPIX/64,2), 256, 0, stream>>>(Yb, rb_ffn_in_w, nullptr, rb_norm2_w, nullptr, nullptr, TB, 128);
  k_dwgate<<<SZ/256, 256, 0, stream>>>(TB, rb_ffn_dw_w, T1);
  k_pw<<<dim3(NPIX/64,1), 256, 0, stream>>>(T1, rb_ffn_out_w, nullptr, nullptr, Xb, Yb, outf, 64);
}

// Round 6
// 653.727 us; speedup vs baseline: 1.5486x; 1.1107x over previous
//
#include <hip/hip_runtime.h>

#define NB 2
#define NC 64
#define NHW 4096
#define NPIX (NB*NHW)          // 8192
#define SZ   (NB*NC*NHW)       // 524288 floats per 64-ch fp32 tensor

__device__ __forceinline__ float clamp01(float v){ return fminf(fmaxf(v, 0.f), 1.f); }

// ---------------------------------------------------------------- reductions
__global__ __launch_bounds__(256) void k_max_hw(const float* __restrict__ in, float* __restrict__ mx){
  int bc = blockIdx.x; int t = threadIdx.x;
  const float* p = in + (size_t)bc*NHW;
  float m = -1e30f;
  for (int n = t; n < NHW; n += 256) m = fmaxf(m, p[n]);
  #pragma unroll
  for (int off = 32; off; off >>= 1) m = fmaxf(m, __shfl_xor(m, off));
  __shared__ float sm[4];
  if ((t & 63) == 0) sm[t >> 6] = m;
  __syncthreads();
  if (t == 0) mx[bc] = fmaxf(fmaxf(sm[0], sm[1]), fmaxf(sm[2], sm[3]));
}

__global__ void k_spe_score(const float* __restrict__ mx, const float* __restrict__ w,
                            const float* __restrict__ bias, float* __restrict__ out){
  int t = threadIdx.x; if (t >= 128) return;
  int b = t >> 6, o = t & 63;
  float acc = bias[o];
  const float* m = mx + b*64;
  for (int i = 0; i < 64; ++i) acc += w[o*64 + i] * m[i];
  out[t] = clamp01(acc);   // relu6 then clip(-1,1) == clamp to [0,1]
}

__global__ __launch_bounds__(256) void k_chmean(const float* __restrict__ in, float* __restrict__ out){
  int p = blockIdx.x*256 + threadIdx.x;         // 0..8191
  int b = p >> 12, n = p & 4095;
  const float* base = in + (size_t)b*NC*NHW + n;
  float s = 0.f;
  #pragma unroll
  for (int c = 0; c < 64; ++c) s += base[c*NHW];
  out[p] = s * (1.0f/64.0f);
}

// ---------------------------------------------------------------- depthwise 3x3 + score adds
__global__ __launch_bounds__(256) void k_dw3(const float* __restrict__ in, const float* __restrict__ w,
    const float* __restrict__ bias, const float* __restrict__ add_bc, const float* __restrict__ chmean,
    const float* __restrict__ spw, const float* __restrict__ spb, float* __restrict__ out){
  int g = blockIdx.x*256 + threadIdx.x;         // B*64*4096
  int pix = g & 4095; int c = (g >> 12) & 63; int b = g >> 18;
  int y = pix >> 6, x = pix & 63;
  const float* base = in + (size_t)(b*64 + c)*NHW;
  float wf[9];
  #pragma unroll
  for (int i = 0; i < 9; ++i) wf[i] = w[c*9 + i];
  float acc = 0.f;
  #pragma unroll
  for (int ky = -1; ky <= 1; ++ky){
    int yy = y + ky; if ((unsigned)yy >= 64u) continue;
    #pragma unroll
    for (int kx = -1; kx <= 1; ++kx){
      int xx = x + kx; if ((unsigned)xx >= 64u) continue;
      acc += base[yy*64 + xx] * wf[(ky+1)*3 + (kx+1)];
    }
  }
  acc += bias[c];
  if (add_bc) acc += add_bc[b*64 + c];
  if (chmean){
    float z = spw[c] * chmean[b*4096 + pix] + spb[c];
    acc += clamp01(z);
  }
  out[g] = acc;
}

// ---------------------------------------------------------------- pointwise conv (64 -> OC), LDS block GEMM
// tile: 32 px x 64 oc; grid (NPIX/32, OC/64); 256 threads -> 4 oc x 2 px each.
// optional fused bias-free LayerNorm on input (lnw); optional in2 added to input
// (and the sum written to add_out by blockIdx.y==0 blocks).
__global__ __launch_bounds__(256) void k_pw(const float* __restrict__ in, const float* __restrict__ w,
    const float* __restrict__ bias, const float* __restrict__ lnw,
    const float* __restrict__ in2, float* __restrict__ add_out,
    const float* __restrict__ r1, const float* __restrict__ r2,
    float* __restrict__ outf, int OC){
  __shared__ __align__(16) float Xs[64][32];
  __shared__ __align__(16) float Wt[64][64];    // [i][o]
  __shared__ float psum[8][32], psqs[8][32];
  __shared__ float invs[32];
  int t = threadIdx.x;
  int ptile = blockIdx.x; int oc0 = blockIdx.y*64;
  int b = ptile >> 7; int n0 = (ptile & 127)*32;
  const float* inb = in + (size_t)b*64*NHW + n0;
  const float* inb2 = in2 ? in2 + (size_t)b*64*NHW + n0 : nullptr;
  float* aob = add_out ? add_out + (size_t)b*64*NHW + n0 : nullptr;
  float ps = 0.f, pss = 0.f;
  #pragma unroll
  for (int k = 0; k < 8; ++k){
    int i = k*8 + (t >> 5); int n = t & 31;
    float v = inb[(size_t)i*NHW + n];
    if (inb2) v += inb2[(size_t)i*NHW + n];
    Xs[i][n] = v;
    if (aob && blockIdx.y == 0) aob[(size_t)i*NHW + n] = v;
    ps += v; pss += v*v;
  }
  if (lnw){ psum[t>>5][t&31] = ps; psqs[t>>5][t&31] = pss; }
  #pragma unroll
  for (int k = 0; k < 16; ++k){
    int idx = k*256 + t; int o = idx & 63, i = idx >> 6;
    float wv = w[(oc0 + o)*64 + i];
    if (lnw) wv *= lnw[i];
    Wt[i][o] = wv;
  }
  __syncthreads();
  if (lnw){
    if (t < 32){
      float s1 = 0.f, s2 = 0.f;
      #pragma unroll
      for (int g = 0; g < 8; ++g){ s1 += psum[g][t]; s2 += psqs[g][t]; }
      float mu = s1*(1.0f/64.0f);
      float var = s2*(1.0f/64.0f) - mu*mu;
      invs[t] = rsqrtf(fmaxf(var, 0.f) + 1e-5f);
    }
    __syncthreads();
  }
  int tn = t & 15, to = t >> 4;
  float a0x=0,a0y=0,a1x=0,a1y=0,a2x=0,a2y=0,a3x=0,a3y=0;
  #pragma unroll
  for (int i = 0; i < 64; ++i){
    const float2 xv = *(const float2*)&Xs[i][tn*2];
    const float4 wv = *(const float4*)&Wt[i][to*4];
    a0x += wv.x*xv.x; a0y += wv.x*xv.y;
    a1x += wv.y*xv.x; a1y += wv.y*xv.y;
    a2x += wv.z*xv.x; a2y += wv.z*xv.y;
    a3x += wv.w*xv.x; a3y += wv.w*xv.y;
  }
  float sx = 1.f, sy = 1.f;
  if (lnw){ sx = invs[tn*2+0]; sy = invs[tn*2+1]; }
  float ax[4] = {a0x,a1x,a2x,a3x}, ay[4] = {a0y,a1y,a2y,a3y};
  #pragma unroll
  for (int oo = 0; oo < 4; ++oo){
    int o = oc0 + to*4 + oo;
    float bv = bias ? bias[o] : 0.f;
    size_t obase = ((size_t)b*OC + o)*NHW + n0 + tn*2;
    float v0 = ax[oo]*sx + bv, v1 = ay[oo]*sy + bv;
    if (r1){ v0 += r1[obase+0]; v1 += r1[obase+1]; }
    if (r2){ v0 += r2[obase+0]; v1 += r2[obase+1]; }
    float2 vv; vv.x = v0; vv.y = v1;
    *(float2*)(outf + obase) = vv;
  }
}

// ---------------------------------------------------------------- flash cross-attention, hd=16, n=4096
// grid 1024 = qt(32) x bh(8) x chunk(4); block 256 = 32 q-groups x 8 key-splits.
// No LDS, no barriers: K/V are L2-resident (512KB per bh), read direct.
// chunk c covers keys [c*1024,(c+1)*1024); partials merged by k_fcomb.
__global__ __launch_bounds__(256, 3) void k_flash(const float* __restrict__ Q, const float* __restrict__ K,
                                                  const float* __restrict__ V, float* __restrict__ Pacc,
                                                  float* __restrict__ Pm, float* __restrict__ Pl){
  int blk = blockIdx.x;
  int qt = blk & 31; int bh = (blk >> 5) & 7; int c = blk >> 8;
  size_t cbase = (size_t)bh*16*NHW;
  int t = threadIdx.x;
  int s = t & 7, qg = t >> 3;
  int q0 = qt*128 + qg*4;
  const float* Kp = K + cbase + c*1024;
  const float* Vp = V + cbase + c*1024;
  float qv[4][16];
  #pragma unroll
  for (int qq = 0; qq < 4; ++qq)
    #pragma unroll
    for (int d = 0; d < 16; ++d)
      qv[qq][d] = Q[cbase + d*NHW + q0 + qq] * 0.25f;   // fold 1/sqrt(16)
  float m[4], l[4], acc[4][16];
  #pragma unroll
  for (int qq = 0; qq < 4; ++qq){
    m[qq] = -1e30f; l[qq] = 0.f;
    #pragma unroll
    for (int d = 0; d < 16; ++d) acc[qq][d] = 0.f;
  }
  for (int kb = 0; kb < 1024; kb += 64){
    int kk = kb + s*4;
    float sc[4][8];
    #pragma unroll
    for (int qq = 0; qq < 4; ++qq)
      #pragma unroll
      for (int e = 0; e < 8; ++e) sc[qq][e] = 0.f;
    #pragma unroll
    for (int d = 0; d < 16; ++d){
      const float4 ka = *(const float4*)&Kp[(size_t)d*NHW + kk];
      const float4 kb_ = *(const float4*)&Kp[(size_t)d*NHW + kk + 32];
      #pragma unroll
      for (int qq = 0; qq < 4; ++qq){
        float qd = qv[qq][d];
        sc[qq][0] += qd*ka.x;  sc[qq][1] += qd*ka.y;  sc[qq][2] += qd*ka.z;  sc[qq][3] += qd*ka.w;
        sc[qq][4] += qd*kb_.x; sc[qq][5] += qd*kb_.y; sc[qq][6] += qd*kb_.z; sc[qq][7] += qd*kb_.w;
      }
    }
    #pragma unroll
    for (int qq = 0; qq < 4; ++qq){
      float m8 = fmaxf(fmaxf(fmaxf(sc[qq][0],sc[qq][1]),fmaxf(sc[qq][2],sc[qq][3])),
                       fmaxf(fmaxf(sc[qq][4],sc[qq][5]),fmaxf(sc[qq][6],sc[qq][7])));
      float mn = fmaxf(m[qq], m8);
      float f  = __expf(m[qq] - mn);
      float ssum = 0.f;
      #pragma unroll
      for (int e = 0; e < 8; ++e){ sc[qq][e] = __expf(sc[qq][e]-mn); ssum += sc[qq][e]; }
      l[qq] = l[qq]*f + ssum;
      m[qq] = mn;
      #pragma unroll
      for (int d = 0; d < 16; ++d) acc[qq][d] *= f;
    }
    #pragma unroll
    for (int d = 0; d < 16; ++d){
      const float4 va = *(const float4*)&Vp[(size_t)d*NHW + kk];
      const float4 vb = *(const float4*)&Vp[(size_t)d*NHW + kk + 32];
      #pragma unroll
      for (int qq = 0; qq < 4; ++qq){
        acc[qq][d] += sc[qq][0]*va.x + sc[qq][1]*va.y + sc[qq][2]*va.z + sc[qq][3]*va.w
                    + sc[qq][4]*vb.x + sc[qq][5]*vb.y + sc[qq][6]*vb.z + sc[qq][7]*vb.w;
      }
    }
  }
  // merge 8 key-splits (lanes t&7)
  #pragma unroll
  for (int off = 1; off <= 4; off <<= 1){
    #pragma unroll
    for (int qq = 0; qq < 4; ++qq){
      float mo = __shfl_xor(m[qq], off);
      float lo = __shfl_xor(l[qq], off);
      float mn = fmaxf(m[qq], mo);
      float fa = __expf(m[qq] - mn), fb = __expf(mo - mn);
      l[qq] = l[qq]*fa + lo*fb;
      #pragma unroll
      for (int d = 0; d < 16; ++d){
        float ao = __shfl_xor(acc[qq][d], off);
        acc[qq][d] = acc[qq][d]*fa + ao*fb;
      }
      m[qq] = mn;
    }
  }
  if (s == 0){
    int pb = c*8 + bh;
    #pragma unroll
    for (int qq = 0; qq < 4; ++qq){
      Pm[(size_t)pb*4096 + q0 + qq] = m[qq];
      Pl[(size_t)pb*4096 + q0 + qq] = l[qq];
      #pragma unroll
      for (int d = 0; d < 16; ++d)
        Pacc[((size_t)pb*16 + d)*4096 + q0 + qq] = acc[qq][d];
    }
  }
}

// combine the 4 key-chunks -> final O  (grid 128, block 256)
__global__ __launch_bounds__(256) void k_fcomb(const float* __restrict__ Pacc, const float* __restrict__ Pm,
                                               const float* __restrict__ Pl, float* __restrict__ O){
  int tid = blockIdx.x*256 + threadIdx.x;       // 0..32767
  int q = tid & 4095; int bh = tid >> 12;
  float mv[4], lv[4];
  float mn = -1e30f;
  #pragma unroll
  for (int c = 0; c < 4; ++c){
    mv[c] = Pm[(size_t)(c*8+bh)*4096 + q];
    lv[c] = Pl[(size_t)(c*8+bh)*4096 + q];
    mn = fmaxf(mn, mv[c]);
  }
  float f[4]; float L = 0.f;
  #pragma unroll
  for (int c = 0; c < 4; ++c){ f[c] = __expf(mv[c]-mn); L += lv[c]*f[c]; }
  float inv = 1.0f / L;
  size_t cbase = (size_t)bh*16*NHW;
  #pragma unroll
  for (int d = 0; d < 16; ++d){
    float o = 0.f;
    #pragma unroll
    for (int c = 0; c < 4; ++c)
      o += Pacc[((size_t)(c*8+bh)*16 + d)*4096 + q] * f[c];
    O[cbase + (size_t)d*NHW + q] = o*inv;
  }
}

// ---------------------------------------------------------------- FFN dw3x3 + chunk + gelu gate (128->64)
__global__ __launch_bounds__(256) void k_dwgate(const float* __restrict__ in, const float* __restrict__ w,
                                                float* __restrict__ out){
  int g = blockIdx.x*256 + threadIdx.x;         // B*64*4096
  int pix = g & 4095; int c = (g >> 12) & 63; int b = g >> 18;
  int y = pix >> 6, x = pix & 63;
  const float* p1 = in + ((size_t)b*128 + c)*NHW;
  const float* p2 = in + ((size_t)b*128 + 64 + c)*NHW;
  float w1[9], w2[9];
  #pragma unroll
  for (int i = 0; i < 9; ++i){ w1[i] = w[c*9+i]; w2[i] = w[(64+c)*9+i]; }
  float a = 0.f, bb = 0.f;
  #pragma unroll
  for (int ky = -1; ky <= 1; ++ky){
    int yy = y + ky; if ((unsigned)yy >= 64u) continue;
    #pragma unroll
    for (int kx = -1; kx <= 1; ++kx){
      int xx = x + kx; if ((unsigned)xx >= 64u) continue;
      int off = yy*64 + xx; int wi = (ky+1)*3 + (kx+1);
      a  += p1[off]*w1[wi];
      bb += p2[off]*w2[wi];
    }
  }
  float gl = 0.5f*a*(1.0f + erff(a*0.70710678118654752f));   // exact gelu
  out[g] = gl*bb;
}

// ---------------------------------------------------------------- dw3x3 on 192 channels (restormer qkv)
__global__ __launch_bounds__(256) void k_dw192(const float* __restrict__ in, const float* __restrict__ w,
                                               float* __restrict__ out){
  int g = blockIdx.x*256 + threadIdx.x;         // B*192*4096
  int pix = g & 4095; int bc = g >> 12; int c = bc % 192;
  int y = pix >> 6, x = pix & 63;
  const float* p = in + (size_t)bc*NHW;
  float wf[9];
  #pragma unroll
  for (int i = 0; i < 9; ++i) wf[i] = w[c*9+i];
  float acc = 0.f;
  #pragma unroll
  for (int ky = -1; ky <= 1; ++ky){
    int yy = y + ky; if ((unsigned)yy >= 64u) continue;
    #pragma unroll
    for (int kx = -1; kx <= 1; ++kx){
      int xx = x + kx; if ((unsigned)xx >= 64u) continue;
      acc += p[yy*64 + xx]*wf[(ky+1)*3 + (kx+1)];
    }
  }
  out[g] = acc;
}

// ---------------------------------------------------------------- restormer channel attention
// k_rnorm: grid 256 = b*128 + r (r 0..63 = q rows, 64..127 = k rows); row L2 norms
__global__ __launch_bounds__(256) void k_rnorm(const float* __restrict__ qkv, float* __restrict__ norms){
  int blk = blockIdx.x; int b = blk >> 7, r = blk & 127;
  int t = threadIdx.x;
  const float* p = qkv + ((size_t)b*192 + r)*NHW;
  float ss = 0.f;
  for (int i = t*4; i < NHW; i += 1024){
    float4 v = *(const float4*)(p + i);
    ss += v.x*v.x + v.y*v.y + v.z*v.z + v.w*v.w;
  }
  #pragma unroll
  for (int off = 32; off; off >>= 1) ss += __shfl_xor(ss, off);
  __shared__ float sm[4];
  if ((t & 63) == 0) sm[t >> 6] = ss;
  __syncthreads();
  if (t == 0) norms[blk] = fmaxf(sqrtf(sm[0]+sm[1]+sm[2]+sm[3]), 1e-12f);
}

// k_rattn2: grid 128 = ((b*4+h)*16 + rq); one output row per block
__global__ __launch_bounds__(256) void k_rattn2(const float* __restrict__ qkv, const float* __restrict__ norms,
                                                const float* __restrict__ temp, float* __restrict__ out){
  int blk = blockIdx.x; int rq = blk & 15, h = (blk >> 4) & 3, b = blk >> 6;
  int t = threadIdx.x;
  const float* bq = qkv + ((size_t)b*192 + h*16 + rq)*NHW;
  const float* bk = qkv + ((size_t)b*192 + 64 + h*16)*NHW;
  float p[16];
  #pragma unroll
  for (int rk = 0; rk < 16; ++rk) p[rk] = 0.f;
  for (int n = t*4; n < NHW; n += 1024){
    float4 qv4 = *(const float4*)(bq + n);
    #pragma unroll
    for (int rk = 0; rk < 16; ++rk){
      float4 kv = *(const float4*)(bk + (size_t)rk*NHW + n);
      p[rk] += qv4.x*kv.x + qv4.y*kv.y + qv4.z*kv.z + qv4.w*kv.w;
    }
  }
  #pragma unroll
  for (int rk = 0; rk < 16; ++rk)
    #pragma unroll
    for (int off = 32; off; off >>= 1) p[rk] += __shfl_xor(p[rk], off);
  __shared__ float red[4][16];
  if ((t & 63) == 0){
    int wv_ = t >> 6;
    #pragma unroll
    for (int rk = 0; rk < 16; ++rk) red[wv_][rk] = p[rk];
  }
  __syncthreads();
  __shared__ float attn[16];
  if (t == 0){
    float nq = norms[b*128 + h*16 + rq];
    float tp = temp[h];
    float e[16]; float mm = -1e30f;
    #pragma unroll
    for (int rk = 0; rk < 16; ++rk){
      float dot = red[0][rk]+red[1][rk]+red[2][rk]+red[3][rk];
      e[rk] = dot/(nq*norms[b*128 + 64 + h*16 + rk]) * tp;
      mm = fmaxf(mm, e[rk]);
    }
    float ssum = 0.f;
    #pragma unroll
    for (int rk = 0; rk < 16; ++rk){ e[rk] = __expf(e[rk]-mm); ssum += e[rk]; }
    float is = 1.f/ssum;
    #pragma unroll
    for (int rk = 0; rk < 16; ++rk) attn[rk] = e[rk]*is;
  }
  __syncthreads();
  float aw[16];
  #pragma unroll
  for (int rk = 0; rk < 16; ++rk) aw[rk] = attn[rk];
  const float* vb = qkv + ((size_t)b*192 + 128 + h*16)*NHW;
  float* ob = out + ((size_t)b*64 + h*16 + rq)*NHW;
  for (int n = t*4; n < NHW; n += 1024){
    float4 o; o.x = 0.f; o.y = 0.f; o.z = 0.f; o.w = 0.f;
    #pragma unroll
    for (int rk = 0; rk < 16; ++rk){
      float4 v = *(const float4*)(vb + (size_t)rk*NHW + n);
      o.x += aw[rk]*v.x; o.y += aw[rk]*v.y; o.z += aw[rk]*v.z; o.w += aw[rk]*v.w;
    }
    *(float4*)(ob + n) = o;
  }
}

// ================================================================ host
extern "C" void kernel_launch(void* const* d_in, const int* in_sizes, int n_in,
                              void* d_out, int out_size, void* d_ws, size_t ws_size,
                              hipStream_t stream){
  const float* hsi_f0     = (const float*)d_in[0];
  const float* msi_f0     = (const float*)d_in[1];
  const float* hsi_fi     = (const float*)d_in[2];
  const float* msi_fi     = (const float*)d_in[3];
  const float* sp_mlp_w   = (const float*)d_in[4];
  const float* sp_mlp_b   = (const float*)d_in[5];
  const float* spe_mlp_w  = (const float*)d_in[6];
  const float* spe_mlp_b  = (const float*)d_in[7];
  const float* spa_dw_w   = (const float*)d_in[8];
  const float* spa_dw_b   = (const float*)d_in[9];
  const float* spa_pw_w   = (const float*)d_in[10];
  const float* spa_pw_b   = (const float*)d_in[11];
  const float* spe_dw_w   = (const float*)d_in[12];
  const float* spe_dw_b   = (const float*)d_in[13];
  const float* spe_pw_w   = (const float*)d_in[14];
  const float* spe_pw_b   = (const float*)d_in[15];
  const float* sb_q_w     = (const float*)d_in[16];
  const float* sb_q_b     = (const float*)d_in[17];
  const float* sb_k_w     = (const float*)d_in[18];
  const float* sb_k_b     = (const float*)d_in[19];
  const float* sb_v_w     = (const float*)d_in[20];
  const float* sb_v_b     = (const float*)d_in[21];
  const float* sb_o_w     = (const float*)d_in[22];
  const float* sb_o_b     = (const float*)d_in[23];
  const float* sb_norm2_w = (const float*)d_in[24];
  const float* sb_ffn_in_w  = (const float*)d_in[25];
  const float* sb_ffn_dw_w  = (const float*)d_in[26];
  const float* sb_ffn_out_w = (const float*)d_in[27];
  const float* rb_norm1_w = (const float*)d_in[28];
  const float* rb_temp    = (const float*)d_in[29];
  const float* rb_qkv_w   = (const float*)d_in[30];
  const float* rb_qkv_dw_w= (const float*)d_in[31];
  const float* rb_proj_w  = (const float*)d_in[32];
  const float* rb_norm2_w = (const float*)d_in[33];
  const float* rb_ffn_in_w  = (const float*)d_in[34];
  const float* rb_ffn_dw_w  = (const float*)d_in[35];
  const float* rb_ffn_out_w = (const float*)d_in[36];

  float* W   = (float*)d_ws;
  float* Hb  = W;                 // hsi branch output      [B][64][HW]
  float* Mb  = W + (size_t)SZ;    // msi branch output
  float* Xb  = W + (size_t)2*SZ;  // x1
  float* Yb  = W + (size_t)3*SZ;  // y
  float* T1  = W + (size_t)4*SZ;  // Q during flash; O after fcomb; QKV[0] later
  float* T2  = W + (size_t)5*SZ;  // K
  float* T3  = W + (size_t)6*SZ;  // V
  float* QKV = T1;                // 3*SZ contiguous (T1..T3) for restormer qkv
  float* TB  = W + (size_t)7*SZ;  // 2*SZ (128-ch ffn buffer / attn out)
  float* TB2 = W + (size_t)9*SZ;  // 3*SZ (192-ch pre-dw qkv)
  float* Pacc= W + (size_t)7*SZ;         // 4*SZ flash partial acc (dead before TB/TB2 used)
  float* Pm  = W + (size_t)11*SZ;        // 131072
  float* Pl  = W + (size_t)11*SZ + 131072; // 131072
  float* mxb = W + (size_t)12*SZ;        // 128
  float* speb= mxb + 128;                // 128
  float* cmb = speb + 128;               // 8192
  float* normb = W + (size_t)12*SZ + 9216; // 256

  float* outf = (float*)d_out;

  // scores
  k_max_hw  <<<NB*NC, 256, 0, stream>>>(hsi_fi, mxb);
  k_spe_score<<<1, 128, 0, stream>>>(mxb, spe_mlp_w, spe_mlp_b, speb);
  k_chmean  <<<NPIX/256, 256, 0, stream>>>(msi_fi, cmb);
  // hsi branch
  k_dw3<<<SZ/256, 256, 0, stream>>>(hsi_f0, spe_dw_w, spe_dw_b, speb, nullptr, nullptr, nullptr, T1);
  k_pw<<<dim3(NPIX/32,1), 256, 0, stream>>>(T1, spe_pw_w, spe_pw_b, nullptr, nullptr, nullptr, nullptr, nullptr, Hb, 64);
  // msi branch
  k_dw3<<<SZ/256, 256, 0, stream>>>(msi_f0, spa_dw_w, spa_dw_b, nullptr, cmb, sp_mlp_w, sp_mlp_b, T1);
  k_pw<<<dim3(NPIX/32,1), 256, 0, stream>>>(T1, spa_pw_w, spa_pw_b, nullptr, nullptr, nullptr, nullptr, nullptr, Mb, 64);
  // cross-attention Q,K,V
  k_pw<<<dim3(NPIX/32,1), 256, 0, stream>>>(Mb, sb_q_w, sb_q_b, nullptr, nullptr, nullptr, nullptr, nullptr, T1, 64);
  k_pw<<<dim3(NPIX/32,1), 256, 0, stream>>>(Hb, sb_k_w, sb_k_b, nullptr, nullptr, nullptr, nullptr, nullptr, T2, 64);
  k_pw<<<dim3(NPIX/32,1), 256, 0, stream>>>(Hb, sb_v_w, sb_v_b, nullptr, nullptr, nullptr, nullptr, nullptr, T3, 64);
  k_flash<<<1024, 256, 0, stream>>>(T1, T2, T3, Pacc, Pm, Pl);
  k_fcomb<<<128, 256, 0, stream>>>(Pacc, Pm, Pl, T1);
  k_pw<<<dim3(NPIX/32,1), 256, 0, stream>>>(T1, sb_o_w, sb_o_b, nullptr, nullptr, nullptr, Mb, nullptr, Xb, 64);  // +msi residual
  // SpectralBlock FFN (LayerNorm fused into the 1x1 conv)
  k_pw<<<dim3(NPIX/32,2), 256, 0, stream>>>(Xb, sb_ffn_in_w, nullptr, sb_norm2_w, nullptr, nullptr, nullptr, nullptr, TB, 128);
  k_dwgate<<<SZ/256, 256, 0, stream>>>(TB, sb_ffn_dw_w, T1);
  k_pw<<<dim3(NPIX/32,1), 256, 0, stream>>>(T1, sb_ffn_out_w, nullptr, nullptr, nullptr, nullptr, Xb, nullptr, Xb, 64);
  // RestormerBlock: y = Hb+Mb computed in-staging (written to Yb), LN fused
  k_pw<<<dim3(NPIX/32,3), 256, 0, stream>>>(Hb, rb_qkv_w, nullptr, rb_norm1_w, Mb, Yb, nullptr, nullptr, TB2, 192);
  k_dw192<<<3*SZ/256, 256, 0, stream>>>(TB2, rb_qkv_dw_w, QKV);
  k_rnorm<<<256, 256, 0, stream>>>(QKV, normb);
  k_rattn2<<<128, 256, 0, stream>>>(QKV, normb, rb_temp, TB);
  k_pw<<<dim3(NPIX/32,1), 256, 0, stream>>>(TB, rb_proj_w, nullptr, nullptr, nullptr, nullptr, Yb, nullptr, Yb, 64);
  // Restormer FFN + final combine: out = x1 + (y + ffn(ln(y)))
  k_pw<<<dim3(NPIX/32,2), 256, 0, stream>>>(Yb, rb_ffn_in_w, nullptr, rb_norm2_w, nullptr, nullptr, nullptr, nullptr, TB, 128);
  k_dwgate<<<SZ/256, 256, 0, stream>>>(TB, rb_ffn_dw_w, T1);
  k_pw<<<dim3(NPIX/32,1), 256, 0, stream>>>(T1, rb_ffn_out_w, nullptr, nullptr, nullptr, nullptr, Xb, Yb, outf, 64);
}

// Round 7
// 537.673 us; speedup vs baseline: 1.8828x; 1.2158x over previous
//
#include <hip/hip_runtime.h>

#define NB 2
#define NC 64
#define NHW 4096
#define NPIX (NB*NHW)          // 8192
#define SZ   (NB*NC*NHW)       // 524288 floats per 64-ch fp32 tensor

__device__ __forceinline__ float clamp01(float v){ return fminf(fmaxf(v, 0.f), 1.f); }

// ---------------------------------------------------------------- reductions
__global__ __launch_bounds__(256) void k_max_hw(const float* __restrict__ in, float* __restrict__ mx){
  int bc = blockIdx.x; int t = threadIdx.x;
  const float* p = in + (size_t)bc*NHW;
  float m = -1e30f;
  for (int n = t; n < NHW; n += 256) m = fmaxf(m, p[n]);
  #pragma unroll
  for (int off = 32; off; off >>= 1) m = fmaxf(m, __shfl_xor(m, off));
  __shared__ float sm[4];
  if ((t & 63) == 0) sm[t >> 6] = m;
  __syncthreads();
  if (t == 0) mx[bc] = fmaxf(fmaxf(sm[0], sm[1]), fmaxf(sm[2], sm[3]));
}

__global__ void k_spe_score(const float* __restrict__ mx, const float* __restrict__ w,
                            const float* __restrict__ bias, float* __restrict__ out){
  int t = threadIdx.x; if (t >= 128) return;
  int b = t >> 6, o = t & 63;
  float acc = bias[o];
  const float* m = mx + b*64;
  for (int i = 0; i < 64; ++i) acc += w[o*64 + i] * m[i];
  out[t] = clamp01(acc);   // relu6 then clip(-1,1) == clamp to [0,1]
}

__global__ __launch_bounds__(256) void k_chmean(const float* __restrict__ in, float* __restrict__ out){
  int p = blockIdx.x*256 + threadIdx.x;         // 0..8191
  int b = p >> 12, n = p & 4095;
  const float* base = in + (size_t)b*NC*NHW + n;
  float s = 0.f;
  #pragma unroll
  for (int c = 0; c < 64; ++c) s += base[c*NHW];
  out[p] = s * (1.0f/64.0f);
}

// ---------------------------------------------------------------- depthwise 3x3 + score adds
__global__ __launch_bounds__(256) void k_dw3(const float* __restrict__ in, const float* __restrict__ w,
    const float* __restrict__ bias, const float* __restrict__ add_bc, const float* __restrict__ chmean,
    const float* __restrict__ spw, const float* __restrict__ spb, float* __restrict__ out){
  int g = blockIdx.x*256 + threadIdx.x;         // B*64*4096
  int pix = g & 4095; int c = (g >> 12) & 63; int b = g >> 18;
  int y = pix >> 6, x = pix & 63;
  const float* base = in + (size_t)(b*64 + c)*NHW;
  float wf[9];
  #pragma unroll
  for (int i = 0; i < 9; ++i) wf[i] = w[c*9 + i];
  float acc = 0.f;
  #pragma unroll
  for (int ky = -1; ky <= 1; ++ky){
    int yy = y + ky; if ((unsigned)yy >= 64u) continue;
    #pragma unroll
    for (int kx = -1; kx <= 1; ++kx){
      int xx = x + kx; if ((unsigned)xx >= 64u) continue;
      acc += base[yy*64 + xx] * wf[(ky+1)*3 + (kx+1)];
    }
  }
  acc += bias[c];
  if (add_bc) acc += add_bc[b*64 + c];
  if (chmean){
    float z = spw[c] * chmean[b*4096 + pix] + spb[c];
    acc += clamp01(z);
  }
  out[g] = acc;
}

// ---------------------------------------------------------------- pointwise conv (64 -> OC), LDS block GEMM
// tile: 32 px x 64 oc; grid (NPIX/32, OC/64); 256 threads -> 4 oc x 2 px each.
__global__ __launch_bounds__(256) void k_pw(const float* __restrict__ in, const float* __restrict__ w,
    const float* __restrict__ bias, const float* __restrict__ lnw,
    const float* __restrict__ in2, float* __restrict__ add_out,
    const float* __restrict__ r1, const float* __restrict__ r2,
    float* __restrict__ outf, int OC){
  __shared__ __align__(16) float Xs[64][32];
  __shared__ __align__(16) float Wt[64][64];    // [i][o]
  __shared__ float psum[8][32], psqs[8][32];
  __shared__ float invs[32];
  int t = threadIdx.x;
  int ptile = blockIdx.x; int oc0 = blockIdx.y*64;
  int b = ptile >> 7; int n0 = (ptile & 127)*32;
  const float* inb = in + (size_t)b*64*NHW + n0;
  const float* inb2 = in2 ? in2 + (size_t)b*64*NHW + n0 : nullptr;
  float* aob = add_out ? add_out + (size_t)b*64*NHW + n0 : nullptr;
  float ps = 0.f, pss = 0.f;
  #pragma unroll
  for (int k = 0; k < 8; ++k){
    int i = k*8 + (t >> 5); int n = t & 31;
    float v = inb[(size_t)i*NHW + n];
    if (inb2) v += inb2[(size_t)i*NHW + n];
    Xs[i][n] = v;
    if (aob && blockIdx.y == 0) aob[(size_t)i*NHW + n] = v;
    ps += v; pss += v*v;
  }
  if (lnw){ psum[t>>5][t&31] = ps; psqs[t>>5][t&31] = pss; }
  #pragma unroll
  for (int k = 0; k < 16; ++k){
    int idx = k*256 + t; int o = idx & 63, i = idx >> 6;
    float wv = w[(oc0 + o)*64 + i];
    if (lnw) wv *= lnw[i];
    Wt[i][o] = wv;
  }
  __syncthreads();
  if (lnw){
    if (t < 32){
      float s1 = 0.f, s2 = 0.f;
      #pragma unroll
      for (int g = 0; g < 8; ++g){ s1 += psum[g][t]; s2 += psqs[g][t]; }
      float mu = s1*(1.0f/64.0f);
      float var = s2*(1.0f/64.0f) - mu*mu;
      invs[t] = rsqrtf(fmaxf(var, 0.f) + 1e-5f);
    }
    __syncthreads();
  }
  int tn = t & 15, to = t >> 4;
  float a0x=0,a0y=0,a1x=0,a1y=0,a2x=0,a2y=0,a3x=0,a3y=0;
  #pragma unroll
  for (int i = 0; i < 64; ++i){
    const float2 xv = *(const float2*)&Xs[i][tn*2];
    const float4 wv = *(const float4*)&Wt[i][to*4];
    a0x += wv.x*xv.x; a0y += wv.x*xv.y;
    a1x += wv.y*xv.x; a1y += wv.y*xv.y;
    a2x += wv.z*xv.x; a2y += wv.z*xv.y;
    a3x += wv.w*xv.x; a3y += wv.w*xv.y;
  }
  float sx = 1.f, sy = 1.f;
  if (lnw){ sx = invs[tn*2+0]; sy = invs[tn*2+1]; }
  float ax[4] = {a0x,a1x,a2x,a3x}, ay[4] = {a0y,a1y,a2y,a3y};
  #pragma unroll
  for (int oo = 0; oo < 4; ++oo){
    int o = oc0 + to*4 + oo;
    float bv = bias ? bias[o] : 0.f;
    size_t obase = ((size_t)b*OC + o)*NHW + n0 + tn*2;
    float v0 = ax[oo]*sx + bv, v1 = ay[oo]*sy + bv;
    if (r1){ v0 += r1[obase+0]; v1 += r1[obase+1]; }
    if (r2){ v0 += r2[obase+0]; v1 += r2[obase+1]; }
    float2 vv; vv.x = v0; vv.y = v1;
    *(float2*)(outf + obase) = vv;
  }
}

// ---------------------------------------------------------------- flash cross-attention, hd=16, n=4096
// grid 1024 = qt(64) x bh(8) x chunk(2); block 256 = 32 q-groups x 8 key-splits.
// 2 queries/thread keeps live state ~90 floats -> no spill, ~4 waves/SIMD.
// No LDS/barriers: K/V are L2-resident (512KB per bh). chunk c covers keys
// [c*2048,(c+1)*2048); partials merged by k_fcomb.
__global__ __launch_bounds__(256) void k_flash(const float* __restrict__ Q, const float* __restrict__ K,
                                               const float* __restrict__ V, float* __restrict__ Pacc,
                                               float* __restrict__ Pm, float* __restrict__ Pl){
  int blk = blockIdx.x;
  int qt = blk & 63; int bh = (blk >> 6) & 7; int c = blk >> 9;
  size_t cbase = (size_t)bh*16*NHW;
  int t = threadIdx.x;
  int s = t & 7, qg = t >> 3;
  int q0 = qt*64 + qg*2;
  const float* Kp = K + cbase + c*2048;
  const float* Vp = V + cbase + c*2048;
  float qv[2][16];
  #pragma unroll
  for (int qq = 0; qq < 2; ++qq)
    #pragma unroll
    for (int d = 0; d < 16; ++d)
      qv[qq][d] = Q[cbase + d*NHW + q0 + qq] * 0.25f;   // fold 1/sqrt(16)
  float m[2], l[2], acc[2][16];
  #pragma unroll
  for (int qq = 0; qq < 2; ++qq){
    m[qq] = -1e30f; l[qq] = 0.f;
    #pragma unroll
    for (int d = 0; d < 16; ++d) acc[qq][d] = 0.f;
  }
  for (int kb = 0; kb < 2048; kb += 64){
    int kk = kb + s*4;
    float sc[2][8];
    #pragma unroll
    for (int qq = 0; qq < 2; ++qq)
      #pragma unroll
      for (int e = 0; e < 8; ++e) sc[qq][e] = 0.f;
    #pragma unroll
    for (int d = 0; d < 16; ++d){
      const float4 ka = *(const float4*)&Kp[(size_t)d*NHW + kk];
      const float4 kb_ = *(const float4*)&Kp[(size_t)d*NHW + kk + 32];
      #pragma unroll
      for (int qq = 0; qq < 2; ++qq){
        float qd = qv[qq][d];
        sc[qq][0] += qd*ka.x;  sc[qq][1] += qd*ka.y;  sc[qq][2] += qd*ka.z;  sc[qq][3] += qd*ka.w;
        sc[qq][4] += qd*kb_.x; sc[qq][5] += qd*kb_.y; sc[qq][6] += qd*kb_.z; sc[qq][7] += qd*kb_.w;
      }
    }
    #pragma unroll
    for (int qq = 0; qq < 2; ++qq){
      float m8 = fmaxf(fmaxf(fmaxf(sc[qq][0],sc[qq][1]),fmaxf(sc[qq][2],sc[qq][3])),
                       fmaxf(fmaxf(sc[qq][4],sc[qq][5]),fmaxf(sc[qq][6],sc[qq][7])));
      float mn = fmaxf(m[qq], m8);
      float f  = __expf(m[qq] - mn);
      float ssum = 0.f;
      #pragma unroll
      for (int e = 0; e < 8; ++e){ sc[qq][e] = __expf(sc[qq][e]-mn); ssum += sc[qq][e]; }
      l[qq] = l[qq]*f + ssum;
      m[qq] = mn;
      #pragma unroll
      for (int d = 0; d < 16; ++d) acc[qq][d] *= f;
    }
    #pragma unroll
    for (int d = 0; d < 16; ++d){
      const float4 va = *(const float4*)&Vp[(size_t)d*NHW + kk];
      const float4 vb = *(const float4*)&Vp[(size_t)d*NHW + kk + 32];
      #pragma unroll
      for (int qq = 0; qq < 2; ++qq){
        acc[qq][d] += sc[qq][0]*va.x + sc[qq][1]*va.y + sc[qq][2]*va.z + sc[qq][3]*va.w
                    + sc[qq][4]*vb.x + sc[qq][5]*vb.y + sc[qq][6]*vb.z + sc[qq][7]*vb.w;
      }
    }
  }
  // merge 8 key-splits (lanes t&7)
  #pragma unroll
  for (int off = 1; off <= 4; off <<= 1){
    #pragma unroll
    for (int qq = 0; qq < 2; ++qq){
      float mo = __shfl_xor(m[qq], off);
      float lo = __shfl_xor(l[qq], off);
      float mn = fmaxf(m[qq], mo);
      float fa = __expf(m[qq] - mn), fb = __expf(mo - mn);
      l[qq] = l[qq]*fa + lo*fb;
      #pragma unroll
      for (int d = 0; d < 16; ++d){
        float ao = __shfl_xor(acc[qq][d], off);
        acc[qq][d] = acc[qq][d]*fa + ao*fb;
      }
      m[qq] = mn;
    }
  }
  if (s == 0){
    int pb = c*8 + bh;
    #pragma unroll
    for (int qq = 0; qq < 2; ++qq){
      Pm[(size_t)pb*4096 + q0 + qq] = m[qq];
      Pl[(size_t)pb*4096 + q0 + qq] = l[qq];
      #pragma unroll
      for (int d = 0; d < 16; ++d)
        Pacc[((size_t)pb*16 + d)*4096 + q0 + qq] = acc[qq][d];
    }
  }
}

// combine the 2 key-chunks -> final O  (grid 128, block 256)
__global__ __launch_bounds__(256) void k_fcomb(const float* __restrict__ Pacc, const float* __restrict__ Pm,
                                               const float* __restrict__ Pl, float* __restrict__ O){
  int tid = blockIdx.x*256 + threadIdx.x;       // 0..32767
  int q = tid & 4095; int bh = tid >> 12;
  float m0 = Pm[(size_t)bh*4096 + q],      m1 = Pm[(size_t)(8+bh)*4096 + q];
  float l0 = Pl[(size_t)bh*4096 + q],      l1 = Pl[(size_t)(8+bh)*4096 + q];
  float mn = fmaxf(m0, m1);
  float f0 = __expf(m0 - mn), f1 = __expf(m1 - mn);
  float inv = 1.0f / (l0*f0 + l1*f1);
  size_t cbase = (size_t)bh*16*NHW;
  #pragma unroll
  for (int d = 0; d < 16; ++d){
    float a0 = Pacc[((size_t)bh*16 + d)*4096 + q];
    float a1 = Pacc[((size_t)(8+bh)*16 + d)*4096 + q];
    O[cbase + (size_t)d*NHW + q] = (a0*f0 + a1*f1)*inv;
  }
}

// ---------------------------------------------------------------- FFN dw3x3 + chunk + gelu gate (128->64)
__global__ __launch_bounds__(256) void k_dwgate(const float* __restrict__ in, const float* __restrict__ w,
                                                float* __restrict__ out){
  int g = blockIdx.x*256 + threadIdx.x;         // B*64*4096
  int pix = g & 4095; int c = (g >> 12) & 63; int b = g >> 18;
  int y = pix >> 6, x = pix & 63;
  const float* p1 = in + ((size_t)b*128 + c)*NHW;
  const float* p2 = in + ((size_t)b*128 + 64 + c)*NHW;
  float w1[9], w2[9];
  #pragma unroll
  for (int i = 0; i < 9; ++i){ w1[i] = w[c*9+i]; w2[i] = w[(64+c)*9+i]; }
  float a = 0.f, bb = 0.f;
  #pragma unroll
  for (int ky = -1; ky <= 1; ++ky){
    int yy = y + ky; if ((unsigned)yy >= 64u) continue;
    #pragma unroll
    for (int kx = -1; kx <= 1; ++kx){
      int xx = x + kx; if ((unsigned)xx >= 64u) continue;
      int off = yy*64 + xx; int wi = (ky+1)*3 + (kx+1);
      a  += p1[off]*w1[wi];
      bb += p2[off]*w2[wi];
    }
  }
  float gl = 0.5f*a*(1.0f + erff(a*0.70710678118654752f));   // exact gelu
  out[g] = gl*bb;
}

// ---------------------------------------------------------------- dw3x3 on 192 channels (restormer qkv)
__global__ __launch_bounds__(256) void k_dw192(const float* __restrict__ in, const float* __restrict__ w,
                                               float* __restrict__ out){
  int g = blockIdx.x*256 + threadIdx.x;         // B*192*4096
  int pix = g & 4095; int bc = g >> 12; int c = bc % 192;
  int y = pix >> 6, x = pix & 63;
  const float* p = in + (size_t)bc*NHW;
  float wf[9];
  #pragma unroll
  for (int i = 0; i < 9; ++i) wf[i] = w[c*9+i];
  float acc = 0.f;
  #pragma unroll
  for (int ky = -1; ky <= 1; ++ky){
    int yy = y + ky; if ((unsigned)yy >= 64u) continue;
    #pragma unroll
    for (int kx = -1; kx <= 1; ++kx){
      int xx = x + kx; if ((unsigned)xx >= 64u) continue;
      acc += p[yy*64 + xx]*wf[(ky+1)*3 + (kx+1)];
    }
  }
  out[g] = acc;
}

// ---------------------------------------------------------------- restormer channel attention
// k_rnorm: grid 256 = b*128 + r (r 0..63 = q rows, 64..127 = k rows); row L2 norms
__global__ __launch_bounds__(256) void k_rnorm(const float* __restrict__ qkv, float* __restrict__ norms){
  int blk = blockIdx.x; int b = blk >> 7, r = blk & 127;
  int t = threadIdx.x;
  const float* p = qkv + ((size_t)b*192 + r)*NHW;
  float ss = 0.f;
  for (int i = t*4; i < NHW; i += 1024){
    float4 v = *(const float4*)(p + i);
    ss += v.x*v.x + v.y*v.y + v.z*v.z + v.w*v.w;
  }
  #pragma unroll
  for (int off = 32; off; off >>= 1) ss += __shfl_xor(ss, off);
  __shared__ float sm[4];
  if ((t & 63) == 0) sm[t >> 6] = ss;
  __syncthreads();
  if (t == 0) norms[blk] = fmaxf(sqrtf(sm[0]+sm[1]+sm[2]+sm[3]), 1e-12f);
}

// k_rattn2: grid 128 = ((b*4+h)*16 + rq); one output row per block
__global__ __launch_bounds__(256) void k_rattn2(const float* __restrict__ qkv, const float* __restrict__ norms,
                                                const float* __restrict__ temp, float* __restrict__ out){
  int blk = blockIdx.x; int rq = blk & 15, h = (blk >> 4) & 3, b = blk >> 6;
  int t = threadIdx.x;
  const float* bq = qkv + ((size_t)b*192 + h*16 + rq)*NHW;
  const float* bk = qkv + ((size_t)b*192 + 64 + h*16)*NHW;
  float p[16];
  #pragma unroll
  for (int rk = 0; rk < 16; ++rk) p[rk] = 0.f;
  for (int n = t*4; n < NHW; n += 1024){
    float4 qv4 = *(const float4*)(bq + n);
    #pragma unroll
    for (int rk = 0; rk < 16; ++rk){
      float4 kv = *(const float4*)(bk + (size_t)rk*NHW + n);
      p[rk] += qv4.x*kv.x + qv4.y*kv.y + qv4.z*kv.z + qv4.w*kv.w;
    }
  }
  #pragma unroll
  for (int rk = 0; rk < 16; ++rk)
    #pragma unroll
    for (int off = 32; off; off >>= 1) p[rk] += __shfl_xor(p[rk], off);
  __shared__ float red[4][16];
  if ((t & 63) == 0){
    int wv_ = t >> 6;
    #pragma unroll
    for (int rk = 0; rk < 16; ++rk) red[wv_][rk] = p[rk];
  }
  __syncthreads();
  __shared__ float attn[16];
  if (t == 0){
    float nq = norms[b*128 + h*16 + rq];
    float tp = temp[h];
    float e[16]; float mm = -1e30f;
    #pragma unroll
    for (int rk = 0; rk < 16; ++rk){
      float dot = red[0][rk]+red[1][rk]+red[2][rk]+red[3][rk];
      e[rk] = dot/(nq*norms[b*128 + 64 + h*16 + rk]) * tp;
      mm = fmaxf(mm, e[rk]);
    }
    float ssum = 0.f;
    #pragma unroll
    for (int rk = 0; rk < 16; ++rk){ e[rk] = __expf(e[rk]-mm); ssum += e[rk]; }
    float is = 1.f/ssum;
    #pragma unroll
    for (int rk = 0; rk < 16; ++rk) attn[rk] = e[rk]*is;
  }
  __syncthreads();
  float aw[16];
  #pragma unroll
  for (int rk = 0; rk < 16; ++rk) aw[rk] = attn[rk];
  const float* vb = qkv + ((size_t)b*192 + 128 + h*16)*NHW;
  float* ob = out + ((size_t)b*64 + h*16 + rq)*NHW;
  for (int n = t*4; n < NHW; n += 1024){
    float4 o; o.x = 0.f; o.y = 0.f; o.z = 0.f; o.w = 0.f;
    #pragma unroll
    for (int rk = 0; rk < 16; ++rk){
      float4 v = *(const float4*)(vb + (size_t)rk*NHW + n);
      o.x += aw[rk]*v.x; o.y += aw[rk]*v.y; o.z += aw[rk]*v.z; o.w += aw[rk]*v.w;
    }
    *(float4*)(ob + n) = o;
  }
}

// ================================================================ host
extern "C" void kernel_launch(void* const* d_in, const int* in_sizes, int n_in,
                              void* d_out, int out_size, void* d_ws, size_t ws_size,
                              hipStream_t stream){
  const float* hsi_f0     = (const float*)d_in[0];
  const float* msi_f0     = (const float*)d_in[1];
  const float* hsi_fi     = (const float*)d_in[2];
  const float* msi_fi     = (const float*)d_in[3];
  const float* sp_mlp_w   = (const float*)d_in[4];
  const float* sp_mlp_b   = (const float*)d_in[5];
  const float* spe_mlp_w  = (const float*)d_in[6];
  const float* spe_mlp_b  = (const float*)d_in[7];
  const float* spa_dw_w   = (const float*)d_in[8];
  const float* spa_dw_b   = (const float*)d_in[9];
  const float* spa_pw_w   = (const float*)d_in[10];
  const float* spa_pw_b   = (const float*)d_in[11];
  const float* spe_dw_w   = (const float*)d_in[12];
  const float* spe_dw_b   = (const float*)d_in[13];
  const float* spe_pw_w   = (const float*)d_in[14];
  const float* spe_pw_b   = (const float*)d_in[15];
  const float* sb_q_w     = (const float*)d_in[16];
  const float* sb_q_b     = (const float*)d_in[17];
  const float* sb_k_w     = (const float*)d_in[18];
  const float* sb_k_b     = (const float*)d_in[19];
  const float* sb_v_w     = (const float*)d_in[20];
  const float* sb_v_b     = (const float*)d_in[21];
  const float* sb_o_w     = (const float*)d_in[22];
  const float* sb_o_b     = (const float*)d_in[23];
  const float* sb_norm2_w = (const float*)d_in[24];
  const float* sb_ffn_in_w  = (const float*)d_in[25];
  const float* sb_ffn_dw_w  = (const float*)d_in[26];
  const float* sb_ffn_out_w = (const float*)d_in[27];
  const float* rb_norm1_w = (const float*)d_in[28];
  const float* rb_temp    = (const float*)d_in[29];
  const float* rb_qkv_w   = (const float*)d_in[30];
  const float* rb_qkv_dw_w= (const float*)d_in[31];
  const float* rb_proj_w  = (const float*)d_in[32];
  const float* rb_norm2_w = (const float*)d_in[33];
  const float* rb_ffn_in_w  = (const float*)d_in[34];
  const float* rb_ffn_dw_w  = (const float*)d_in[35];
  const float* rb_ffn_out_w = (const float*)d_in[36];

  float* W   = (float*)d_ws;
  float* Hb  = W;                 // hsi branch output      [B][64][HW]
  float* Mb  = W + (size_t)SZ;    // msi branch output
  float* Xb  = W + (size_t)2*SZ;  // x1
  float* Yb  = W + (size_t)3*SZ;  // y
  float* T1  = W + (size_t)4*SZ;  // Q during flash; O after fcomb; QKV[0] later
  float* T2  = W + (size_t)5*SZ;  // K
  float* T3  = W + (size_t)6*SZ;  // V
  float* QKV = T1;                // 3*SZ contiguous (T1..T3) for restormer qkv
  float* TB  = W + (size_t)7*SZ;  // 2*SZ (128-ch ffn buffer / attn out)
  float* TB2 = W + (size_t)9*SZ;  // 3*SZ (192-ch pre-dw qkv)
  float* Pacc= W + (size_t)7*SZ;         // 2*SZ flash partial acc (dead before TB/TB2 used)
  float* Pm  = W + (size_t)11*SZ;        // 65536
  float* Pl  = W + (size_t)11*SZ + 65536; // 65536
  float* mxb = W + (size_t)12*SZ;        // 128
  float* speb= mxb + 128;                // 128
  float* cmb = speb + 128;               // 8192
  float* normb = W + (size_t)12*SZ + 9216; // 256

  float* outf = (float*)d_out;

  // scores
  k_max_hw  <<<NB*NC, 256, 0, stream>>>(hsi_fi, mxb);
  k_spe_score<<<1, 128, 0, stream>>>(mxb, spe_mlp_w, spe_mlp_b, speb);
  k_chmean  <<<NPIX/256, 256, 0, stream>>>(msi_fi, cmb);
  // hsi branch
  k_dw3<<<SZ/256, 256, 0, stream>>>(hsi_f0, spe_dw_w, spe_dw_b, speb, nullptr, nullptr, nullptr, T1);
  k_pw<<<dim3(NPIX/32,1), 256, 0, stream>>>(T1, spe_pw_w, spe_pw_b, nullptr, nullptr, nullptr, nullptr, nullptr, Hb, 64);
  // msi branch
  k_dw3<<<SZ/256, 256, 0, stream>>>(msi_f0, spa_dw_w, spa_dw_b, nullptr, cmb, sp_mlp_w, sp_mlp_b, T1);
  k_pw<<<dim3(NPIX/32,1), 256, 0, stream>>>(T1, spa_pw_w, spa_pw_b, nullptr, nullptr, nullptr, nullptr, nullptr, Mb, 64);
  // cross-attention Q,K,V
  k_pw<<<dim3(NPIX/32,1), 256, 0, stream>>>(Mb, sb_q_w, sb_q_b, nullptr, nullptr, nullptr, nullptr, nullptr, T1, 64);
  k_pw<<<dim3(NPIX/32,1), 256, 0, stream>>>(Hb, sb_k_w, sb_k_b, nullptr, nullptr, nullptr, nullptr, nullptr, T2, 64);
  k_pw<<<dim3(NPIX/32,1), 256, 0, stream>>>(Hb, sb_v_w, sb_v_b, nullptr, nullptr, nullptr, nullptr, nullptr, T3, 64);
  k_flash<<<1024, 256, 0, stream>>>(T1, T2, T3, Pacc, Pm, Pl);
  k_fcomb<<<128, 256, 0, stream>>>(Pacc, Pm, Pl, T1);
  k_pw<<<dim3(NPIX/32,1), 256, 0, stream>>>(T1, sb_o_w, sb_o_b, nullptr, nullptr, nullptr, Mb, nullptr, Xb, 64);  // +msi residual
  // SpectralBlock FFN (LayerNorm fused into the 1x1 conv)
  k_pw<<<dim3(NPIX/32,2), 256, 0, stream>>>(Xb, sb_ffn_in_w, nullptr, sb_norm2_w, nullptr, nullptr, nullptr, nullptr, TB, 128);
  k_dwgate<<<SZ/256, 256, 0, stream>>>(TB, sb_ffn_dw_w, T1);
  k_pw<<<dim3(NPIX/32,1), 256, 0, stream>>>(T1, sb_ffn_out_w, nullptr, nullptr, nullptr, nullptr, Xb, nullptr, Xb, 64);
  // RestormerBlock: y = Hb+Mb computed in-staging (written to Yb), LN fused
  k_pw<<<dim3(NPIX/32,3), 256, 0, stream>>>(Hb, rb_qkv_w, nullptr, rb_norm1_w, Mb, Yb, nullptr, nullptr, TB2, 192);
  k_dw192<<<3*SZ/256, 256, 0, stream>>>(TB2, rb_qkv_dw_w, QKV);
  k_rnorm<<<256, 256, 0, stream>>>(QKV, normb);
  k_rattn2<<<128, 256, 0, stream>>>(QKV, normb, rb_temp, TB);
  k_pw<<<dim3(NPIX/32,1), 256, 0, stream>>>(TB, rb_proj_w, nullptr, nullptr, nullptr, nullptr, Yb, nullptr, Yb, 64);
  // Restormer FFN + final combine: out = x1 + (y + ffn(ln(y)))
  k_pw<<<dim3(NPIX/32,2), 256, 0, stream>>>(Yb, rb_ffn_in_w, nullptr, rb_norm2_w, nullptr, nullptr, nullptr, nullptr, TB, 128);
  k_dwgate<<<SZ/256, 256, 0, stream>>>(TB, rb_ffn_dw_w, T1);
  k_pw<<<dim3(NPIX/32,1), 256, 0, stream>>>(T1, rb_ffn_out_w, nullptr, nullptr, nullptr, nullptr, Xb, Yb, outf, 64);
}